// Round 10
// baseline (1657.981 us; speedup 1.0000x reference)
//
#include <hip/hip_runtime.h>

// ---------------------------------------------------------------------------
// Transducer forward (RNN-T). R9:
//  - Projection collapse: Wce = jW1[:, :P]@encPW, Wcd = jW1[:, P:]@dPW
//    precomputed (k_gemmT) -> penc/pdec each one GEMM from h1s/hds.
//  - k_joint: unrolled, double-buffered jW2 fragment prefetch.
//  - LSTM L1: phase-split (ih-half computed while sibling h1 publish lands).
// Sync: per-step write-once sentinel buffers (0xFFFFFFFF = f16 NaN pair),
// guard-then-verify polling, RELAXED agent-scope atomics.
// ---------------------------------------------------------------------------

typedef _Float16 f16;
typedef _Float16 f16x8 __attribute__((ext_vector_type(8)));
typedef float f32x4 __attribute__((ext_vector_type(4)));
using u32 = unsigned int;

#define BB   8
#define TT   256
#define UU1  65      // U+1
#define HH   512
#define G4   2048    // 4*H
#define PP   512
#define JJ   512
#define VV   1024
#define SENT 0xFFFFFFFFu

#define LOADX(p)     __hip_atomic_load((p), __ATOMIC_RELAXED, __HIP_MEMORY_SCOPE_AGENT)
#define STOREX(p, v) __hip_atomic_store((p), (v), __ATOMIC_RELAXED, __HIP_MEMORY_SCOPE_AGENT)

static __device__ __forceinline__ u32 packf16(float a, float b) {
  f16 ha = (f16)a, hb = (f16)b;
  unsigned short ua = __builtin_bit_cast(unsigned short, ha);
  unsigned short ub = __builtin_bit_cast(unsigned short, hb);
  return (u32)ua | ((u32)ub << 16);
}
static __device__ __forceinline__ float sigm(float x) {
  x = fminf(30.f, fmaxf(-30.f, x));
  return __builtin_amdgcn_rcpf(1.f + __expf(-x));
}
static __device__ __forceinline__ float ftanh(float x) {
  x = fminf(15.f, fmaxf(-15.f, x));
  float t = __expf(2.f * x);
  return (t - 1.f) * __builtin_amdgcn_rcpf(t + 1.f);
}

// ---------------------------- utility kernels ------------------------------
__global__ void k_init(u32* __restrict__ p, int n, int z1, int z2) {
  int i = blockIdx.x * 256 + threadIdx.x;
  if (i >= n) return;
  bool z = (i < 2048) | ((u32)(i - z1) < 2048u) | ((u32)(i - z2) < 2048u);
  p[i] = z ? 0u : SENT;
}

// merged f32 -> f16 cast over weight segments (one launch)
struct CastSeg { const float* s; f16* d; int n4; };
struct CastArgs { CastSeg seg[10]; };
__global__ void k_cast_all(CastArgs a, int total4) {
  int i = blockIdx.x * 256 + threadIdx.x;
  if (i >= total4) return;
  int k = 0, off = i;
  while (off >= a.seg[k].n4) { off -= a.seg[k].n4; ++k; }
  const float4 v = *(const float4*)(a.seg[k].s + (size_t)off * 4);
  uint2 p; p.x = packf16(v.x, v.y); p.y = packf16(v.z, v.w);
  *(uint2*)(a.seg[k].d + (size_t)off * 4) = p;
}

// e[row][0:512] = embed[ys_p[row]] ; row = b*65+u ; ys_p[b][0]=BOS=0
__global__ void k_embed(const int* __restrict__ ys, const float* __restrict__ emb,
                        float* __restrict__ e) {
  int row = blockIdx.x;                 // 0..519
  int b = row / UU1, u = row % UU1;
  int idx = (u == 0) ? 0 : ys[b * (UU1 - 1) + (u - 1)];
  const float4* s = (const float4*)(emb + (size_t)idx * HH);
  float4* d = (float4*)(e + (size_t)row * HH);
  d[threadIdx.x] = s[threadIdx.x];      // 128 threads x 16B = 2KB
}

// bce[j] = dot(jW1[j, :512], encPb); bcd[j] = dot(jW1[j, 512:], dPb) + jb1[j]
__global__ void k_biasdot(const float* __restrict__ jW1, const float* __restrict__ encPb,
                          const float* __restrict__ dPb, const float* __restrict__ jb1,
                          float* __restrict__ bce, float* __restrict__ bcd) {
  int j = blockIdx.x * 256 + threadIdx.x;
  if (j >= 512) return;
  const float* rowE = jW1 + (size_t)j * 1024;
  const float* rowD = rowE + 512;
  float s1 = 0.f, s2 = 0.f;
  for (int p = 0; p < 512; p += 4) {
    float4 a = *(const float4*)(rowE + p), b = *(const float4*)(encPb + p);
    s1 += a.x * b.x + a.y * b.y + a.z * b.z + a.w * b.w;
    float4 c = *(const float4*)(rowD + p), d = *(const float4*)(dPb + p);
    s2 += c.x * d.x + c.y * d.y + c.z * d.z + c.w * d.w;
  }
  bce[j] = s1; bcd[j] = s2 + jb1[j];
}

// ------------------------------ generic GEMM -------------------------------
// C[M,N] = A[M,lda](f32) * B[N,ldb](f16)^T (+ bias[n]); MFMA f16 16x16x32.
__global__ __launch_bounds__(256) void k_gemm(
    const float* __restrict__ A, const f16* __restrict__ B,
    const float* __restrict__ bias, float* __restrict__ C,
    int M, int N, int K, int lda, int ldb) {
  __shared__ f16 As[128][72];
  __shared__ f16 Bs[128][72];
  int tid = threadIdx.x;
  int mb = blockIdx.y * 128, nb = blockIdx.x * 128;
  int wave = tid >> 6, lane = tid & 63;
  int wm = wave >> 1, wn = wave & 1;
  int rowa = lane & 15, kg = lane >> 4;
  f32x4 acc[4][4] = {};
  for (int k0 = 0; k0 < K; k0 += 64) {
    for (int idx = tid; idx < 2048; idx += 256) {
      int r = idx >> 4, cq = idx & 15;
      int gm = mb + r, gk = k0 + cq * 4;
      float4 v = make_float4(0.f, 0.f, 0.f, 0.f);
      if (gm < M && gk + 3 < K) v = *(const float4*)(A + (size_t)gm * lda + gk);
      uint2 p; p.x = packf16(v.x, v.y); p.y = packf16(v.z, v.w);
      *(uint2*)&As[r][cq * 4] = p;
    }
    for (int idx = tid; idx < 1024; idx += 256) {
      int r = idx >> 3, c8 = idx & 7;
      int gn = nb + r, gk = k0 + c8 * 8;
      uint4 v = make_uint4(0u, 0u, 0u, 0u);
      if (gn < N && gk + 7 < K) v = *(const uint4*)(B + (size_t)gn * ldb + gk);
      *(uint4*)&Bs[r][c8 * 8] = v;
    }
    __syncthreads();
#pragma unroll
    for (int kf = 0; kf < 2; ++kf) {
      f16x8 af[4], bf[4];
#pragma unroll
      for (int mt = 0; mt < 4; ++mt)
        af[mt] = *(const f16x8*)&As[wm * 64 + mt * 16 + rowa][kf * 32 + kg * 8];
#pragma unroll
      for (int nt = 0; nt < 4; ++nt)
        bf[nt] = *(const f16x8*)&Bs[wn * 64 + nt * 16 + rowa][kf * 32 + kg * 8];
#pragma unroll
      for (int mt = 0; mt < 4; ++mt)
#pragma unroll
        for (int nt = 0; nt < 4; ++nt)
          acc[mt][nt] = __builtin_amdgcn_mfma_f32_16x16x32_f16(af[mt], bf[nt], acc[mt][nt], 0, 0, 0);
    }
    __syncthreads();
  }
#pragma unroll
  for (int nt = 0; nt < 4; ++nt) {
    int gn = nb + wn * 64 + nt * 16 + rowa;
    float bv = bias ? bias[gn] : 0.f;
#pragma unroll
    for (int mt = 0; mt < 4; ++mt)
#pragma unroll
      for (int r = 0; r < 4; ++r) {
        int gm = mb + wm * 64 + mt * 16 + kg * 4 + r;
        if (gm < M) C[(size_t)gm * N + gn] = acc[mt][nt][r] + bv;
      }
  }
}

// ---------------- transposed-B GEMM (weight combine, 512^3) ----------------
// C16[j][h] = sum_p A[j][p](f32) * B2[p][h](f16); M=N=K=512 exact.
__global__ __launch_bounds__(256) void k_gemmT(
    const float* __restrict__ A, int lda, const f16* __restrict__ B2,
    f16* __restrict__ C16) {
  __shared__ f16 As[128][72];
  __shared__ f16 Bs[128][72];
  int tid = threadIdx.x;
  int mb = blockIdx.y * 128, nb = blockIdx.x * 128;
  int wave = tid >> 6, lane = tid & 63;
  int wm = wave >> 1, wn = wave & 1;
  int rowa = lane & 15, kg = lane >> 4;
  f32x4 acc[4][4] = {};
  for (int k0 = 0; k0 < 512; k0 += 64) {
    for (int idx = tid; idx < 2048; idx += 256) {
      int r = idx >> 4, cq = idx & 15;
      float4 v = *(const float4*)(A + (size_t)(mb + r) * lda + k0 + cq * 4);
      uint2 p; p.x = packf16(v.x, v.y); p.y = packf16(v.z, v.w);
      *(uint2*)&As[r][cq * 4] = p;
    }
    // stage B transposed: Bs[n][k] = B2[k0+k][nb+n]
    for (int idx = tid; idx < 1024; idx += 256) {
      int r = idx >> 4, c8 = idx & 15;          // r = k 0..63, c8 = n-octet
      uint4 v = *(const uint4*)(B2 + (size_t)(k0 + r) * 512 + nb + c8 * 8);
      f16 tmp[8]; *(uint4*)tmp = v;
#pragma unroll
      for (int e = 0; e < 8; ++e) Bs[c8 * 8 + e][r] = tmp[e];
    }
    __syncthreads();
#pragma unroll
    for (int kf = 0; kf < 2; ++kf) {
      f16x8 af[4], bf[4];
#pragma unroll
      for (int mt = 0; mt < 4; ++mt)
        af[mt] = *(const f16x8*)&As[wm * 64 + mt * 16 + rowa][kf * 32 + kg * 8];
#pragma unroll
      for (int nt = 0; nt < 4; ++nt)
        bf[nt] = *(const f16x8*)&Bs[wn * 64 + nt * 16 + rowa][kf * 32 + kg * 8];
#pragma unroll
      for (int mt = 0; mt < 4; ++mt)
#pragma unroll
        for (int nt = 0; nt < 4; ++nt)
          acc[mt][nt] = __builtin_amdgcn_mfma_f32_16x16x32_f16(af[mt], bf[nt], acc[mt][nt], 0, 0, 0);
    }
    __syncthreads();
  }
#pragma unroll
  for (int nt = 0; nt < 4; ++nt) {
    int gn = nb + wn * 64 + nt * 16 + rowa;
#pragma unroll
    for (int mt = 0; mt < 4; ++mt)
#pragma unroll
      for (int r = 0; r < 4; ++r) {
        int gm = mb + wm * 64 + mt * 16 + kg * 4 + r;
        C16[(size_t)gm * 512 + gn] = (f16)acc[mt][nt][r];
      }
  }
}

// --------------------- persistent LSTM, sentinel-synced --------------------
template <int NW>
static __device__ __forceinline__ void poll_batch(const u32* const* p, u32* vv) {
#pragma unroll
  for (int k = 0; k < NW; ++k) vv[k] = LOADX(p[k]);   // all in flight
  int gd = 0;
  while (++gd < (1 << 18)) {
    bool any = false;
#pragma unroll
    for (int k = 0; k < NW; ++k) any = any | (vv[k] == SENT);
    if (!any) break;
    __builtin_amdgcn_s_sleep(4);
#pragma unroll
    for (int k = 0; k < NW; ++k)
      if (vv[k] == SENT) vv[k] = LOADX(p[k]);
  }
}
static __device__ __forceinline__ void guard_spin(const u32* gp) {
  u32 v = LOADX(gp);
  int gd = 0;
  while (v == SENT && ++gd < (1 << 18)) {
    __builtin_amdgcn_s_sleep(2);
    v = LOADX(gp);
  }
}

// 32-unit WG (L0 / decoder). Wave w owns units [w*8, w*8+8), ALL 4 gates.
static __device__ __forceinline__ void lstm_16(
    int wg, const float* __restrict__ xp, const f16* __restrict__ Whh,
    u32* __restrict__ hseq,   // [S+1][2048]; slot 0 zeroed, rest sentinel
    float* __restrict__ hs, int S) {
  extern __shared__ char smem[];
  f16 (*W)[520] = (f16(*)[520])smem;                       // 133,120 B
  f16 (*H)[520] = (f16(*)[520])(smem + 133120);            //   8,320 B
  float (*gat)[8][36] = (float(*)[8][36])(smem + 133120 + 8320); // 4,608 B
  const int tid = threadIdx.x;
  const int u0 = wg * 32;
  const int wave = tid >> 6, lane = tid & 63;
  const int rowa = lane & 15, kg = lane >> 4;
  const int b = lane >> 3, ju = lane & 7;          // scalar-phase mapping
  const int uglob = u0 + wave * 8 + ju;

  for (int idx = tid; idx < 128 * 64; idx += 256) {
    int r = idx >> 6, ck = idx & 63;
    int w = r >> 5, g = (r >> 3) & 3, u = r & 7;
    uint4 v = *(const uint4*)(Whh + ((size_t)(g * 512 + u0 + w * 8 + u)) * 512 + ck * 8);
    *(uint4*)&W[r][ck * 8] = v;
  }
  __syncthreads();

  float c = 0.f;
  for (int t = 0; t < S; ++t) {
    const u32* hb = hseq + (size_t)t * 2048;
    if (tid < 16) guard_spin(hb + tid * 16);
    __syncthreads();

    size_t xpo = ((size_t)b * S + t) * (size_t)G4 + uglob;
    float xi = xp[xpo], xf = xp[xpo + 512], xg = xp[xpo + 1024], xo = xp[xpo + 1536];

    const u32* ptr[8];
    u32 vv[8];
#pragma unroll
    for (int k = 0; k < 8; ++k) ptr[k] = hb + ((tid + k * 256) >> 8) * 256 + ((tid + k * 256) & 255);
    poll_batch<8>(ptr, vv);
#pragma unroll
    for (int k = 0; k < 8; ++k) {
      int idx = tid + k * 256;
      ((u32*)H)[(idx >> 8) * 260 + (idx & 255)] = vv[k];
    }
    __syncthreads();  // B2: H ready

    f32x4 acc0 = {0.f, 0.f, 0.f, 0.f}, acc1 = {0.f, 0.f, 0.f, 0.f};
#pragma unroll
    for (int kf = 0; kf < 16; ++kf) {
      f16x8 af = {};
      if (rowa < 8) af = *(const f16x8*)&H[rowa][kf * 32 + kg * 8];
      f16x8 b0 = *(const f16x8*)&W[wave * 32 + rowa][kf * 32 + kg * 8];
      f16x8 b1 = *(const f16x8*)&W[wave * 32 + 16 + rowa][kf * 32 + kg * 8];
      acc0 = __builtin_amdgcn_mfma_f32_16x16x32_f16(af, b0, acc0, 0, 0, 0);
      acc1 = __builtin_amdgcn_mfma_f32_16x16x32_f16(af, b1, acc1, 0, 0, 0);
    }
    if (kg < 2) {
#pragma unroll
      for (int r = 0; r < 4; ++r) {
        gat[wave][kg * 4 + r][rowa] = acc0[r];
        gat[wave][kg * 4 + r][16 + rowa] = acc1[r];
      }
    }
    // wave-local read (lgkmcnt wait auto-inserted; no barrier)
    float gi = gat[wave][b][ju] + xi;
    float gf = gat[wave][b][8 + ju] + xf;
    float gg = gat[wave][b][16 + ju] + xg;
    float go = gat[wave][b][24 + ju] + xo;
    c = sigm(gf) * c + sigm(gi) * ftanh(gg);
    float h = sigm(go) * ftanh(c);

    float hn = __shfl_down(h, 1);
    if ((ju & 1) == 0)
      STOREX(hseq + (size_t)(t + 1) * 2048 + ((b * 512 + uglob) >> 1), packf16(h, hn));
    if (hs) hs[((size_t)b * S + t) * HH + uglob] = h;
  }
}

// 16-unit WG (encoder L1). Wave w owns units [w*4, w*4+4), ALL 4 gates.
// Phase-split: ih (Wih1 x h0(t), usually already available) computed FIRST,
// overlapping the sibling h1(t-1) publish->visibility latency.
static __device__ __forceinline__ void lstm_l1(
    int wg, const float* __restrict__ gb, const f16* __restrict__ Wih,
    const f16* __restrict__ Whh, const u32* __restrict__ hin,
    u32* __restrict__ hseq, float* __restrict__ hs, int S) {
  extern __shared__ char smem[];
  f16 (*W)[1032] = (f16(*)[1032])smem;                      // 132,096 B
  f16 (*H)[1032] = (f16(*)[1032])(smem + 132096);           //  16,512 B
  float (*gat)[8][20] = (float(*)[8][20])(smem + 132096 + 16512); // 2,560 B
  const int tid = threadIdx.x;
  const int u0 = wg * 16;
  const int wave = tid >> 6, lane = tid & 63;
  const int rowa = lane & 15, kg = lane >> 4;
  const int b = lane >> 2, ju = lane & 3;   // valid for lane < 32
  const int uglob = u0 + wave * 4 + ju;

  for (int idx = tid; idx < 64 * 64; idx += 256) {
    int r = idx >> 6, ck = idx & 63;
    int w = r >> 4, g = (r >> 2) & 3, u = r & 3;
    size_t grow = (size_t)(g * 512 + u0 + w * 4 + u) * 512;
    *(uint4*)&W[r][ck * 8]       = *(const uint4*)(Whh + grow + ck * 8);
    *(uint4*)&W[r][512 + ck * 8] = *(const uint4*)(Wih + grow + ck * 8);
  }
  float gbi = 0.f, gbf = 0.f, gbg = 0.f, gbo = 0.f;
  if (lane < 32) {
    gbi = gb[uglob]; gbf = gb[512 + uglob];
    gbg = gb[1024 + uglob]; gbo = gb[1536 + uglob];
  }
  __syncthreads();

  float c = 0.f;
  for (int t = 0; t < S; ++t) {
    const u32* hbS = hseq + (size_t)t * 2048;
    const u32* hbU = hin + (size_t)(t + 1) * 2048;

    // ---- Phase U: upstream h0(t) (L0 runs ahead -> usually no wait) ----
    if (tid < 16) guard_spin(hbU + tid * 16);
    __syncthreads();
    {
      const u32* ptr[8];
      u32 vv[8];
#pragma unroll
      for (int k = 0; k < 8; ++k) {
        int idx = tid + k * 256;
        ptr[k] = hbU + (idx >> 8) * 256 + (idx & 255);
      }
      poll_batch<8>(ptr, vv);
#pragma unroll
      for (int k = 0; k < 8; ++k) {
        int idx = tid + k * 256;
        ((u32*)H)[(idx >> 8) * 516 + 256 + (idx & 255)] = vv[k];
      }
    }
    __syncthreads();
    f32x4 accA = {0.f, 0.f, 0.f, 0.f}, accB = {0.f, 0.f, 0.f, 0.f};
#pragma unroll
    for (int kf = 0; kf < 8; ++kf) {    // ih: K cols 512..1023
      f16x8 afA = {}, afB = {};
      if (rowa < 8) {
        afA = *(const f16x8*)&H[rowa][(16 + kf) * 32 + kg * 8];
        afB = *(const f16x8*)&H[rowa][(24 + kf) * 32 + kg * 8];
      }
      f16x8 bfA = *(const f16x8*)&W[wave * 16 + rowa][(16 + kf) * 32 + kg * 8];
      f16x8 bfB = *(const f16x8*)&W[wave * 16 + rowa][(24 + kf) * 32 + kg * 8];
      accA = __builtin_amdgcn_mfma_f32_16x16x32_f16(afA, bfA, accA, 0, 0, 0);
      accB = __builtin_amdgcn_mfma_f32_16x16x32_f16(afB, bfB, accB, 0, 0, 0);
    }

    // ---- Phase S: sibling h1(t-1) (the recurrence-critical wait) ----
    if (tid < 32) guard_spin(hbS + tid * 8);
    __syncthreads();
    {
      const u32* ptr[8];
      u32 vv[8];
#pragma unroll
      for (int k = 0; k < 8; ++k) {
        int idx = tid + k * 256;
        ptr[k] = hbS + (idx >> 8) * 256 + (idx & 255);
      }
      poll_batch<8>(ptr, vv);
#pragma unroll
      for (int k = 0; k < 8; ++k) {
        int idx = tid + k * 256;
        ((u32*)H)[(idx >> 8) * 516 + (idx & 255)] = vv[k];
      }
    }
    __syncthreads();
#pragma unroll
    for (int kf = 0; kf < 8; ++kf) {    // hh: K cols 0..511
      f16x8 afA = {}, afB = {};
      if (rowa < 8) {
        afA = *(const f16x8*)&H[rowa][kf * 32 + kg * 8];
        afB = *(const f16x8*)&H[rowa][(8 + kf) * 32 + kg * 8];
      }
      f16x8 bfA = *(const f16x8*)&W[wave * 16 + rowa][kf * 32 + kg * 8];
      f16x8 bfB = *(const f16x8*)&W[wave * 16 + rowa][(8 + kf) * 32 + kg * 8];
      accA = __builtin_amdgcn_mfma_f32_16x16x32_f16(afA, bfA, accA, 0, 0, 0);
      accB = __builtin_amdgcn_mfma_f32_16x16x32_f16(afB, bfB, accB, 0, 0, 0);
    }
    if (kg < 2) {
#pragma unroll
      for (int r = 0; r < 4; ++r) gat[wave][kg * 4 + r][rowa] = accA[r] + accB[r];
    }
    if (lane < 32) {
      float gi = gat[wave][b][ju]      + gbi;
      float gf = gat[wave][b][4 + ju]  + gbf;
      float gg = gat[wave][b][8 + ju]  + gbg;
      float go = gat[wave][b][12 + ju] + gbo;
      c = sigm(gf) * c + sigm(gi) * ftanh(gg);
      float h = sigm(go) * ftanh(c);
      float hn = __shfl_down(h, 1);
      if ((ju & 1) == 0)
        STOREX(hseq + (size_t)(t + 1) * 2048 + (b * 256 + (uglob >> 1)), packf16(h, hn));
      hs[((size_t)b * S + t) * HH + uglob] = h;
    }
  }
}

// all three LSTMs in one dispatch (64 WGs)
__global__ __launch_bounds__(256, 1) void k_lstm3(
    const float* xp0, const f16* Whh0, u32* hseq0,
    const float* b1, const f16* Wih1, const f16* Whh1, u32* hseq1, float* h1s,
    const float* xpd, const f16* Whhd, u32* hseqD, float* hds) {
  int g = blockIdx.x;
  if (g < 16)      lstm_16(g, xp0, Whh0, hseq0, nullptr, TT);
  else if (g < 48) lstm_l1(g - 16, b1, Wih1, Whh1, hseq0, hseq1, h1s, TT);
  else             lstm_16(g - 48, xpd, Whhd, hseqD, hds, UU1);
}

// ------------------------------ fused joint --------------------------------
// 64-row M-tile, swapped operands (A = jW2 v-rows, B = Z m-rows) -> f32x4
// nontemporal stores; jW2 fragments double-buffered (prefetch kf+1).
__global__ __launch_bounds__(512) void k_joint(
    const float* __restrict__ pre_enc,   // [B*T][512]   (bce folded in)
    const float* __restrict__ pre_dec,   // [B*65][512]  (bcd folded in)
    const f16* __restrict__ jW2,         // [1024][512] f16
    const float* __restrict__ jb2,
    float* __restrict__ out) {
  extern __shared__ char smem[];
  f16 (*Z)[520] = (f16(*)[520])smem;     // 66,560 B -> 2 blocks/CU
  int tid = threadIdx.x;
  int m0 = blockIdx.x * 64;
  {
    int r = tid >> 3, q = tid & 7;       // 8 threads per row, 64 cols each
    int m = m0 + r;
    int bb = m / (TT * UU1);
    int rem = m % (TT * UU1);
    int t = rem / UU1, u = rem % UU1;
    const float* pe = pre_enc + ((size_t)bb * TT + t) * JJ + q * 64;
    const float* pd = pre_dec + ((size_t)bb * UU1 + u) * JJ + q * 64;
    for (int i = 0; i < 64; i += 8) {
      float4 e0 = *(const float4*)(pe + i);
      float4 e1 = *(const float4*)(pe + i + 4);
      float4 d0 = *(const float4*)(pd + i);
      float4 d1 = *(const float4*)(pd + i + 4);
      float z0 = ftanh(e0.x + d0.x), z1 = ftanh(e0.y + d0.y);
      float z2 = ftanh(e0.z + d0.z), z3 = ftanh(e0.w + d0.w);
      float z4 = ftanh(e1.x + d1.x), z5 = ftanh(e1.y + d1.y);
      float z6 = ftanh(e1.z + d1.z), z7 = ftanh(e1.w + d1.w);
      uint4 p; p.x = packf16(z0, z1); p.y = packf16(z2, z3);
      p.z = packf16(z4, z5); p.w = packf16(z6, z7);
      *(uint4*)&Z[r][q * 64 + i] = p;
    }
  }
  __syncthreads();
  int wave = tid >> 6, lane = tid & 63;
  int wm = wave >> 2, wn = wave & 3;     // 2 x 4 waves over 64 m x 256 v
  int rowa = lane & 15, kg = lane >> 4;
  for (int ch = 0; ch < 4; ++ch) {       // 4 N-chunks of 256
    f32x4 acc[4][2] = {};
    int nb = ch * 256 + wn * 64;
    const f16* wb = jW2 + (size_t)(nb + rowa) * JJ + kg * 8;
    f16x8 afe[4], afo[4];
#pragma unroll
    for (int nt = 0; nt < 4; ++nt)
      afe[nt] = *(const f16x8*)(wb + (size_t)nt * 16 * JJ);       // kf = 0
#pragma unroll
    for (int kp = 0; kp < 8; ++kp) {
      const int kfe = kp * 2, kfo = kp * 2 + 1;
#pragma unroll
      for (int nt = 0; nt < 4; ++nt)                              // prefetch odd
        afo[nt] = *(const f16x8*)(wb + (size_t)nt * 16 * JJ + kfo * 32);
      {
        f16x8 bf0 = *(const f16x8*)&Z[wm * 32 + rowa][kfe * 32 + kg * 8];
        f16x8 bf1 = *(const f16x8*)&Z[wm * 32 + 16 + rowa][kfe * 32 + kg * 8];
#pragma unroll
        for (int nt = 0; nt < 4; ++nt) {
          acc[nt][0] = __builtin_amdgcn_mfma_f32_16x16x32_f16(afe[nt], bf0, acc[nt][0], 0, 0, 0);
          acc[nt][1] = __builtin_amdgcn_mfma_f32_16x16x32_f16(afe[nt], bf1, acc[nt][1], 0, 0, 0);
        }
      }
      if (kp < 7) {
#pragma unroll
        for (int nt = 0; nt < 4; ++nt)                            // prefetch next even
          afe[nt] = *(const f16x8*)(wb + (size_t)nt * 16 * JJ + (kfe + 2) * 32);
      }
      {
        f16x8 bf0 = *(const f16x8*)&Z[wm * 32 + rowa][kfo * 32 + kg * 8];
        f16x8 bf1 = *(const f16x8*)&Z[wm * 32 + 16 + rowa][kfo * 32 + kg * 8];
#pragma unroll
        for (int nt = 0; nt < 4; ++nt) {
          acc[nt][0] = __builtin_amdgcn_mfma_f32_16x16x32_f16(afo[nt], bf0, acc[nt][0], 0, 0, 0);
          acc[nt][1] = __builtin_amdgcn_mfma_f32_16x16x32_f16(afo[nt], bf1, acc[nt][1], 0, 0, 0);
        }
      }
    }
#pragma unroll
    for (int nt = 0; nt < 4; ++nt) {
      int v = nb + nt * 16 + kg * 4;
      float4 bv = *(const float4*)(jb2 + v);
#pragma unroll
      for (int mt = 0; mt < 2; ++mt) {
        int m = m0 + wm * 32 + mt * 16 + rowa;
        f32x4 st;
        st[0] = acc[nt][mt][0] + bv.x;
        st[1] = acc[nt][mt][1] + bv.y;
        st[2] = acc[nt][mt][2] + bv.z;
        st[3] = acc[nt][mt][3] + bv.w;
        __builtin_nontemporal_store(st, (f32x4*)(out + (size_t)m * VV + v));
      }
    }
  }
}

// ------------------------------- host side ---------------------------------
extern "C" void kernel_launch(void* const* d_in, const int* in_sizes, int n_in,
                              void* d_out, int out_size, void* d_ws, size_t ws_size,
                              hipStream_t stream) {
  const float* xs    = (const float*)d_in[0];
  const int*   ys    = (const int*)d_in[1];
  const float* Wih0  = (const float*)d_in[2];
  const float* Whh0  = (const float*)d_in[3];
  const float* b0    = (const float*)d_in[4];
  const float* Wih1  = (const float*)d_in[5];
  const float* Whh1  = (const float*)d_in[6];
  const float* b1    = (const float*)d_in[7];
  const float* encPW = (const float*)d_in[8];
  const float* encPb = (const float*)d_in[9];
  const float* embed = (const float*)d_in[10];
  const float* dWih  = (const float*)d_in[11];
  const float* dWhh  = (const float*)d_in[12];
  const float* db    = (const float*)d_in[13];
  const float* dPW   = (const float*)d_in[14];
  const float* dPb   = (const float*)d_in[15];
  const float* jW1   = (const float*)d_in[16];
  const float* jb1   = (const float*)d_in[17];
  const float* jW2   = (const float*)d_in[18];
  const float* jb2   = (const float*)d_in[19];
  float* out = (float*)d_out;

  char* base = (char*)d_ws;
  size_t off = 0;
  auto alc = [&](size_t bytes) -> char* {
    char* p = base + off;
    off = (off + bytes + 255) & ~(size_t)255;
    return p;
  };
  f16* Wih0h = (f16*)alc((size_t)2048 * 80 * 2);
  f16* Whh0h = (f16*)alc((size_t)2048 * 512 * 2);
  f16* Wih1h = (f16*)alc((size_t)2048 * 512 * 2);
  f16* Whh1h = (f16*)alc((size_t)2048 * 512 * 2);
  f16* dWihh = (f16*)alc((size_t)2048 * 512 * 2);
  f16* dWhhh = (f16*)alc((size_t)2048 * 512 * 2);
  f16* ePWh  = (f16*)alc((size_t)512 * 512 * 2);
  f16* dPWh  = (f16*)alc((size_t)512 * 512 * 2);
  f16* jW2h  = (f16*)alc((size_t)1024 * 512 * 2);
  f16* Wceh  = (f16*)alc((size_t)512 * 512 * 2);   // jW1enc @ encPW
  f16* Wcdh  = (f16*)alc((size_t)512 * 512 * 2);   // jW1dec @ dPW
  float* bce  = (float*)alc((size_t)512 * 4);
  float* bcd  = (float*)alc((size_t)512 * 4);
  float* e    = (float*)alc((size_t)520 * 512 * 4);
  float* xp0  = (float*)alc((size_t)2048 * 2048 * 4);
  float* xpd  = (float*)alc((size_t)520 * 2048 * 4);
  float* h1s  = (float*)alc((size_t)2048 * 512 * 4);
  float* hds  = (float*)alc((size_t)520 * 512 * 4);
  float* penc = (float*)alc((size_t)2048 * 512 * 4);
  float* pdec = (float*)alc((size_t)520 * 512 * 4);
  u32* hseq0 = (u32*)alc((size_t)(TT + 1) * 2048 * 4);   // [257][2048]
  u32* hseq1 = (u32*)alc((size_t)(TT + 1) * 2048 * 4);   // [257][2048]
  u32* hseqD = (u32*)alc((size_t)(UU1 + 1) * 2048 * 4);  // [66][2048]
  if (off > ws_size) return;

  // 1) sentinel init (one launch): fill + zero slot 0 of each sequence
  {
    int n = (int)(((TT + 1) * 2 + (UU1 + 1)) * 2048);
    int z1 = (int)(hseq1 - hseq0), z2 = (int)(hseqD - hseq0);
    k_init<<<dim3((n + 255) / 256), dim3(256), 0, stream>>>(hseq0, n, z1, z2);
  }
  // 2) cast weights to f16 in ONE launch (jW1 no longer cast; used f32)
  {
    CastArgs ca = {};
    auto seg = [&](int i, const float* s, f16* d, size_t n) {
      ca.seg[i].s = s; ca.seg[i].d = d; ca.seg[i].n4 = (int)(n / 4);
    };
    seg(0, Wih0, Wih0h, (size_t)2048 * 80);
    seg(1, Whh0, Whh0h, (size_t)2048 * 512);
    seg(2, Wih1, Wih1h, (size_t)2048 * 512);
    seg(3, Whh1, Whh1h, (size_t)2048 * 512);
    seg(4, dWih, dWihh, (size_t)2048 * 512);
    seg(5, dWhh, dWhhh, (size_t)2048 * 512);
    seg(6, encPW, ePWh, (size_t)512 * 512);
    seg(7, dPW, dPWh, (size_t)512 * 512);
    seg(8, jW2, jW2h, (size_t)1024 * 512);
    int total4 = 0;
    for (int i = 0; i < 9; ++i) total4 += ca.seg[i].n4;
    k_cast_all<<<dim3((total4 + 255) / 256), dim3(256), 0, stream>>>(ca, total4);
  }
  // 3) weight combine: Wce = jW1[:, :512] @ encPW ; Wcd = jW1[:, 512:] @ dPW
  k_gemmT<<<dim3(4, 4), dim3(256), 0, stream>>>(jW1, 1024, ePWh, Wceh);
  k_gemmT<<<dim3(4, 4), dim3(256), 0, stream>>>(jW1 + 512, 1024, dPWh, Wcdh);
  k_biasdot<<<dim3(2), dim3(256), 0, stream>>>(jW1, encPb, dPb, jb1, bce, bcd);

  // 4) embedding (decoder input)
  k_embed<<<dim3(520), dim3(128), 0, stream>>>(ys, embed, e);

  auto gemm = [&](const float* A, const f16* B, const float* bias, float* C,
                  int M, int N, int K, int lda, int ldb) {
    k_gemm<<<dim3(N / 128, (M + 127) / 128), dim3(256), 0, stream>>>(
        A, B, bias, C, M, N, K, lda, ldb);
  };

  // 5) input projections for enc L0 and decoder
  gemm(xs, Wih0h, b0, xp0, 2048, 2048, 80, 80, 80);
  gemm(e, dWihh, db, xpd, 520, 2048, 512, 512, 512);

  // 6) all three LSTMs, sentinel-pipelined, one dispatch (64 WGs)
  k_lstm3<<<dim3(64), dim3(256), 151168, stream>>>(
      xp0, Whh0h, hseq0,
      b1, Wih1h, Whh1h, hseq1, h1s,
      xpd, dWhhh, hseqD, hds);

  // 7) joint pre-activations directly from LSTM outputs (collapsed weights)
  gemm(h1s, Wceh, bce, penc, 2048, 512, 512, 512, 512);
  gemm(hds, Wcdh, bcd, pdec, 520, 512, 512, 512, 512);

  // 8) fused joint: z = tanh(penc+pdec) ; out = z @ jW2^T + jb2
  k_joint<<<dim3(2080), dim3(512), 66560, stream>>>(penc, pdec, jW2h, jb2, out);
}

// Round 11
// 1485.228 us; speedup vs baseline: 1.1163x; 1.1163x over previous
//
#include <hip/hip_runtime.h>

// ---------------------------------------------------------------------------
// Transducer forward (RNN-T). R10:
//  - k_joint rebuilt: Z[128] in LDS + jW2 slices LDS-staged (double-buffered,
//    register-staged uint4) -> MFMA feeds from LDS only; swapped operands ->
//    f32x4 nontemporal stores. Grid 1040 x 512thr.
//  - lstm_l1 reverted to R8 (combined poll, split accumulators).
//  - Projection collapse (Wce/Wcd) kept.
// Sync: per-step write-once sentinel buffers (0xFFFFFFFF = f16 NaN pair),
// guard-then-verify polling, RELAXED agent-scope atomics.
// ---------------------------------------------------------------------------

typedef _Float16 f16;
typedef _Float16 f16x8 __attribute__((ext_vector_type(8)));
typedef float f32x4 __attribute__((ext_vector_type(4)));
using u32 = unsigned int;

#define BB   8
#define TT   256
#define UU1  65      // U+1
#define HH   512
#define G4   2048    // 4*H
#define PP   512
#define JJ   512
#define VV   1024
#define SENT 0xFFFFFFFFu

#define LOADX(p)     __hip_atomic_load((p), __ATOMIC_RELAXED, __HIP_MEMORY_SCOPE_AGENT)
#define STOREX(p, v) __hip_atomic_store((p), (v), __ATOMIC_RELAXED, __HIP_MEMORY_SCOPE_AGENT)

static __device__ __forceinline__ u32 packf16(float a, float b) {
  f16 ha = (f16)a, hb = (f16)b;
  unsigned short ua = __builtin_bit_cast(unsigned short, ha);
  unsigned short ub = __builtin_bit_cast(unsigned short, hb);
  return (u32)ua | ((u32)ub << 16);
}
static __device__ __forceinline__ float sigm(float x) {
  x = fminf(30.f, fmaxf(-30.f, x));
  return __builtin_amdgcn_rcpf(1.f + __expf(-x));
}
static __device__ __forceinline__ float ftanh(float x) {
  x = fminf(15.f, fmaxf(-15.f, x));
  float t = __expf(2.f * x);
  return (t - 1.f) * __builtin_amdgcn_rcpf(t + 1.f);
}

// ---------------------------- utility kernels ------------------------------
__global__ void k_init(u32* __restrict__ p, int n, int z1, int z2) {
  int i = blockIdx.x * 256 + threadIdx.x;
  if (i >= n) return;
  bool z = (i < 2048) | ((u32)(i - z1) < 2048u) | ((u32)(i - z2) < 2048u);
  p[i] = z ? 0u : SENT;
}

struct CastSeg { const float* s; f16* d; int n4; };
struct CastArgs { CastSeg seg[10]; };
__global__ void k_cast_all(CastArgs a, int total4) {
  int i = blockIdx.x * 256 + threadIdx.x;
  if (i >= total4) return;
  int k = 0, off = i;
  while (off >= a.seg[k].n4) { off -= a.seg[k].n4; ++k; }
  const float4 v = *(const float4*)(a.seg[k].s + (size_t)off * 4);
  uint2 p; p.x = packf16(v.x, v.y); p.y = packf16(v.z, v.w);
  *(uint2*)(a.seg[k].d + (size_t)off * 4) = p;
}

// e[row][0:512] = embed[ys_p[row]] ; row = b*65+u ; ys_p[b][0]=BOS=0
__global__ void k_embed(const int* __restrict__ ys, const float* __restrict__ emb,
                        float* __restrict__ e) {
  int row = blockIdx.x;                 // 0..519
  int b = row / UU1, u = row % UU1;
  int idx = (u == 0) ? 0 : ys[b * (UU1 - 1) + (u - 1)];
  const float4* s = (const float4*)(emb + (size_t)idx * HH);
  float4* d = (float4*)(e + (size_t)row * HH);
  d[threadIdx.x] = s[threadIdx.x];      // 128 threads x 16B = 2KB
}

// bce[j] = dot(jW1[j, :512], encPb); bcd[j] = dot(jW1[j, 512:], dPb) + jb1[j]
__global__ void k_biasdot(const float* __restrict__ jW1, const float* __restrict__ encPb,
                          const float* __restrict__ dPb, const float* __restrict__ jb1,
                          float* __restrict__ bce, float* __restrict__ bcd) {
  int j = blockIdx.x * 256 + threadIdx.x;
  if (j >= 512) return;
  const float* rowE = jW1 + (size_t)j * 1024;
  const float* rowD = rowE + 512;
  float s1 = 0.f, s2 = 0.f;
  for (int p = 0; p < 512; p += 4) {
    float4 a = *(const float4*)(rowE + p), b = *(const float4*)(encPb + p);
    s1 += a.x * b.x + a.y * b.y + a.z * b.z + a.w * b.w;
    float4 c = *(const float4*)(rowD + p), d = *(const float4*)(dPb + p);
    s2 += c.x * d.x + c.y * d.y + c.z * d.z + c.w * d.w;
  }
  bce[j] = s1; bcd[j] = s2 + jb1[j];
}

// ------------------------------ generic GEMM -------------------------------
// C[M,N] = A[M,lda](f32) * B[N,ldb](f16)^T (+ bias[n]); MFMA f16 16x16x32.
__global__ __launch_bounds__(256) void k_gemm(
    const float* __restrict__ A, const f16* __restrict__ B,
    const float* __restrict__ bias, float* __restrict__ C,
    int M, int N, int K, int lda, int ldb) {
  __shared__ f16 As[128][72];
  __shared__ f16 Bs[128][72];
  int tid = threadIdx.x;
  int mb = blockIdx.y * 128, nb = blockIdx.x * 128;
  int wave = tid >> 6, lane = tid & 63;
  int wm = wave >> 1, wn = wave & 1;
  int rowa = lane & 15, kg = lane >> 4;
  f32x4 acc[4][4] = {};
  for (int k0 = 0; k0 < K; k0 += 64) {
    for (int idx = tid; idx < 2048; idx += 256) {
      int r = idx >> 4, cq = idx & 15;
      int gm = mb + r, gk = k0 + cq * 4;
      float4 v = make_float4(0.f, 0.f, 0.f, 0.f);
      if (gm < M && gk + 3 < K) v = *(const float4*)(A + (size_t)gm * lda + gk);
      uint2 p; p.x = packf16(v.x, v.y); p.y = packf16(v.z, v.w);
      *(uint2*)&As[r][cq * 4] = p;
    }
    for (int idx = tid; idx < 1024; idx += 256) {
      int r = idx >> 3, c8 = idx & 7;
      int gn = nb + r, gk = k0 + c8 * 8;
      uint4 v = make_uint4(0u, 0u, 0u, 0u);
      if (gn < N && gk + 7 < K) v = *(const uint4*)(B + (size_t)gn * ldb + gk);
      *(uint4*)&Bs[r][c8 * 8] = v;
    }
    __syncthreads();
#pragma unroll
    for (int kf = 0; kf < 2; ++kf) {
      f16x8 af[4], bf[4];
#pragma unroll
      for (int mt = 0; mt < 4; ++mt)
        af[mt] = *(const f16x8*)&As[wm * 64 + mt * 16 + rowa][kf * 32 + kg * 8];
#pragma unroll
      for (int nt = 0; nt < 4; ++nt)
        bf[nt] = *(const f16x8*)&Bs[wn * 64 + nt * 16 + rowa][kf * 32 + kg * 8];
#pragma unroll
      for (int mt = 0; mt < 4; ++mt)
#pragma unroll
        for (int nt = 0; nt < 4; ++nt)
          acc[mt][nt] = __builtin_amdgcn_mfma_f32_16x16x32_f16(af[mt], bf[nt], acc[mt][nt], 0, 0, 0);
    }
    __syncthreads();
  }
#pragma unroll
  for (int nt = 0; nt < 4; ++nt) {
    int gn = nb + wn * 64 + nt * 16 + rowa;
    float bv = bias ? bias[gn] : 0.f;
#pragma unroll
    for (int mt = 0; mt < 4; ++mt)
#pragma unroll
      for (int r = 0; r < 4; ++r) {
        int gm = mb + wm * 64 + mt * 16 + kg * 4 + r;
        if (gm < M) C[(size_t)gm * N + gn] = acc[mt][nt][r] + bv;
      }
  }
}

// ---------------- transposed-B GEMM (weight combine, 512^3) ----------------
// C16[j][h] = sum_p A[j][p](f32) * B2[p][h](f16); M=N=K=512 exact.
__global__ __launch_bounds__(256) void k_gemmT(
    const float* __restrict__ A, int lda, const f16* __restrict__ B2,
    f16* __restrict__ C16) {
  __shared__ f16 As[128][72];
  __shared__ f16 Bs[128][72];
  int tid = threadIdx.x;
  int mb = blockIdx.y * 128, nb = blockIdx.x * 128;
  int wave = tid >> 6, lane = tid & 63;
  int wm = wave >> 1, wn = wave & 1;
  int rowa = lane & 15, kg = lane >> 4;
  f32x4 acc[4][4] = {};
  for (int k0 = 0; k0 < 512; k0 += 64) {
    for (int idx = tid; idx < 2048; idx += 256) {
      int r = idx >> 4, cq = idx & 15;
      float4 v = *(const float4*)(A + (size_t)(mb + r) * lda + k0 + cq * 4);
      uint2 p; p.x = packf16(v.x, v.y); p.y = packf16(v.z, v.w);
      *(uint2*)&As[r][cq * 4] = p;
    }
    for (int idx = tid; idx < 1024; idx += 256) {
      int r = idx >> 4, c8 = idx & 15;          // r = k 0..63, c8 = n-octet
      uint4 v = *(const uint4*)(B2 + (size_t)(k0 + r) * 512 + nb + c8 * 8);
      f16 tmp[8]; *(uint4*)tmp = v;
#pragma unroll
      for (int e = 0; e < 8; ++e) Bs[c8 * 8 + e][r] = tmp[e];
    }
    __syncthreads();
#pragma unroll
    for (int kf = 0; kf < 2; ++kf) {
      f16x8 af[4], bf[4];
#pragma unroll
      for (int mt = 0; mt < 4; ++mt)
        af[mt] = *(const f16x8*)&As[wm * 64 + mt * 16 + rowa][kf * 32 + kg * 8];
#pragma unroll
      for (int nt = 0; nt < 4; ++nt)
        bf[nt] = *(const f16x8*)&Bs[wn * 64 + nt * 16 + rowa][kf * 32 + kg * 8];
#pragma unroll
      for (int mt = 0; mt < 4; ++mt)
#pragma unroll
        for (int nt = 0; nt < 4; ++nt)
          acc[mt][nt] = __builtin_amdgcn_mfma_f32_16x16x32_f16(af[mt], bf[nt], acc[mt][nt], 0, 0, 0);
    }
    __syncthreads();
  }
#pragma unroll
  for (int nt = 0; nt < 4; ++nt) {
    int gn = nb + wn * 64 + nt * 16 + rowa;
#pragma unroll
    for (int mt = 0; mt < 4; ++mt)
#pragma unroll
      for (int r = 0; r < 4; ++r) {
        int gm = mb + wm * 64 + mt * 16 + kg * 4 + r;
        C16[(size_t)gm * 512 + gn] = (f16)acc[mt][nt][r];
      }
  }
}

// --------------------- persistent LSTM, sentinel-synced --------------------
template <int NW>
static __device__ __forceinline__ void poll_batch(const u32* const* p, u32* vv) {
#pragma unroll
  for (int k = 0; k < NW; ++k) vv[k] = LOADX(p[k]);   // all in flight
  int gd = 0;
  while (++gd < (1 << 18)) {
    bool any = false;
#pragma unroll
    for (int k = 0; k < NW; ++k) any = any | (vv[k] == SENT);
    if (!any) break;
    __builtin_amdgcn_s_sleep(4);
#pragma unroll
    for (int k = 0; k < NW; ++k)
      if (vv[k] == SENT) vv[k] = LOADX(p[k]);
  }
}
static __device__ __forceinline__ void guard_spin(const u32* gp) {
  u32 v = LOADX(gp);
  int gd = 0;
  while (v == SENT && ++gd < (1 << 18)) {
    __builtin_amdgcn_s_sleep(2);
    v = LOADX(gp);
  }
}

// 32-unit WG (L0 / decoder). Wave w owns units [w*8, w*8+8), ALL 4 gates.
static __device__ __forceinline__ void lstm_16(
    int wg, const float* __restrict__ xp, const f16* __restrict__ Whh,
    u32* __restrict__ hseq,   // [S+1][2048]; slot 0 zeroed, rest sentinel
    float* __restrict__ hs, int S) {
  extern __shared__ char smem[];
  f16 (*W)[520] = (f16(*)[520])smem;                       // 133,120 B
  f16 (*H)[520] = (f16(*)[520])(smem + 133120);            //   8,320 B
  float (*gat)[8][36] = (float(*)[8][36])(smem + 133120 + 8320); // 4,608 B
  const int tid = threadIdx.x;
  const int u0 = wg * 32;
  const int wave = tid >> 6, lane = tid & 63;
  const int rowa = lane & 15, kg = lane >> 4;
  const int b = lane >> 3, ju = lane & 7;          // scalar-phase mapping
  const int uglob = u0 + wave * 8 + ju;

  for (int idx = tid; idx < 128 * 64; idx += 256) {
    int r = idx >> 6, ck = idx & 63;
    int w = r >> 5, g = (r >> 3) & 3, u = r & 7;
    uint4 v = *(const uint4*)(Whh + ((size_t)(g * 512 + u0 + w * 8 + u)) * 512 + ck * 8);
    *(uint4*)&W[r][ck * 8] = v;
  }
  __syncthreads();

  float c = 0.f;
  for (int t = 0; t < S; ++t) {
    const u32* hb = hseq + (size_t)t * 2048;
    if (tid < 16) guard_spin(hb + tid * 16);
    __syncthreads();

    size_t xpo = ((size_t)b * S + t) * (size_t)G4 + uglob;
    float xi = xp[xpo], xf = xp[xpo + 512], xg = xp[xpo + 1024], xo = xp[xpo + 1536];

    const u32* ptr[8];
    u32 vv[8];
#pragma unroll
    for (int k = 0; k < 8; ++k) ptr[k] = hb + ((tid + k * 256) >> 8) * 256 + ((tid + k * 256) & 255);
    poll_batch<8>(ptr, vv);
#pragma unroll
    for (int k = 0; k < 8; ++k) {
      int idx = tid + k * 256;
      ((u32*)H)[(idx >> 8) * 260 + (idx & 255)] = vv[k];
    }
    __syncthreads();  // B2: H ready

    f32x4 acc0 = {0.f, 0.f, 0.f, 0.f}, acc1 = {0.f, 0.f, 0.f, 0.f};
#pragma unroll
    for (int kf = 0; kf < 16; ++kf) {
      f16x8 af = {};
      if (rowa < 8) af = *(const f16x8*)&H[rowa][kf * 32 + kg * 8];
      f16x8 b0 = *(const f16x8*)&W[wave * 32 + rowa][kf * 32 + kg * 8];
      f16x8 b1 = *(const f16x8*)&W[wave * 32 + 16 + rowa][kf * 32 + kg * 8];
      acc0 = __builtin_amdgcn_mfma_f32_16x16x32_f16(af, b0, acc0, 0, 0, 0);
      acc1 = __builtin_amdgcn_mfma_f32_16x16x32_f16(af, b1, acc1, 0, 0, 0);
    }
    if (kg < 2) {
#pragma unroll
      for (int r = 0; r < 4; ++r) {
        gat[wave][kg * 4 + r][rowa] = acc0[r];
        gat[wave][kg * 4 + r][16 + rowa] = acc1[r];
      }
    }
    // wave-local read (lgkmcnt wait auto-inserted; no barrier)
    float gi = gat[wave][b][ju] + xi;
    float gf = gat[wave][b][8 + ju] + xf;
    float gg = gat[wave][b][16 + ju] + xg;
    float go = gat[wave][b][24 + ju] + xo;
    c = sigm(gf) * c + sigm(gi) * ftanh(gg);
    float h = sigm(go) * ftanh(c);

    float hn = __shfl_down(h, 1);
    if ((ju & 1) == 0)
      STOREX(hseq + (size_t)(t + 1) * 2048 + ((b * 512 + uglob) >> 1), packf16(h, hn));
    if (hs) hs[((size_t)b * S + t) * HH + uglob] = h;
  }
}

// 16-unit WG (encoder L1), R8 form: combined poll (16 words), split acc.
static __device__ __forceinline__ void lstm_l1(
    int wg, const float* __restrict__ gb, const f16* __restrict__ Wih,
    const f16* __restrict__ Whh, const u32* __restrict__ hin,
    u32* __restrict__ hseq, float* __restrict__ hs, int S) {
  extern __shared__ char smem[];
  f16 (*W)[1032] = (f16(*)[1032])smem;                      // 132,096 B
  f16 (*H)[1032] = (f16(*)[1032])(smem + 132096);           //  16,512 B
  float (*gat)[8][20] = (float(*)[8][20])(smem + 132096 + 16512); // 2,560 B
  const int tid = threadIdx.x;
  const int u0 = wg * 16;
  const int wave = tid >> 6, lane = tid & 63;
  const int rowa = lane & 15, kg = lane >> 4;
  const int b = lane >> 2, ju = lane & 3;   // valid for lane < 32
  const int uglob = u0 + wave * 4 + ju;

  for (int idx = tid; idx < 64 * 64; idx += 256) {
    int r = idx >> 6, ck = idx & 63;
    int w = r >> 4, g = (r >> 2) & 3, u = r & 3;
    size_t grow = (size_t)(g * 512 + u0 + w * 4 + u) * 512;
    *(uint4*)&W[r][ck * 8]       = *(const uint4*)(Whh + grow + ck * 8);
    *(uint4*)&W[r][512 + ck * 8] = *(const uint4*)(Wih + grow + ck * 8);
  }
  float gbi = 0.f, gbf = 0.f, gbg = 0.f, gbo = 0.f;
  if (lane < 32) {
    gbi = gb[uglob]; gbf = gb[512 + uglob];
    gbg = gb[1024 + uglob]; gbo = gb[1536 + uglob];
  }
  __syncthreads();

  float c = 0.f;
  for (int t = 0; t < S; ++t) {
    const u32* hbS = hseq + (size_t)t * 2048;
    const u32* hbU = hin + (size_t)(t + 1) * 2048;
    if (tid < 32)       guard_spin(hbS + tid * 8);
    else if (tid < 48)  guard_spin(hbU + (tid - 32) * 16);
    __syncthreads();
    const u32* ptr[16];
    u32 vv[16];
#pragma unroll
    for (int k = 0; k < 8; ++k) {
      int idx = tid + k * 256;
      int r = idx >> 8, cu = idx & 255;
      ptr[k] = hbS + r * 256 + cu;
      ptr[k + 8] = hbU + r * 256 + cu;
    }
    poll_batch<16>(ptr, vv);
#pragma unroll
    for (int k = 0; k < 8; ++k) {
      int idx = tid + k * 256;
      int r = idx >> 8, cu = idx & 255;
      ((u32*)H)[r * 516 + cu] = vv[k];
      ((u32*)H)[r * 516 + 256 + cu] = vv[k + 8];
    }
    __syncthreads();  // B2

    f32x4 accA = {0.f, 0.f, 0.f, 0.f}, accB = {0.f, 0.f, 0.f, 0.f};
#pragma unroll
    for (int kf = 0; kf < 16; ++kf) {
      f16x8 afA = {}, afB = {};
      if (rowa < 8) {
        afA = *(const f16x8*)&H[rowa][kf * 32 + kg * 8];
        afB = *(const f16x8*)&H[rowa][(kf + 16) * 32 + kg * 8];
      }
      f16x8 bfA = *(const f16x8*)&W[wave * 16 + rowa][kf * 32 + kg * 8];
      f16x8 bfB = *(const f16x8*)&W[wave * 16 + rowa][(kf + 16) * 32 + kg * 8];
      accA = __builtin_amdgcn_mfma_f32_16x16x32_f16(afA, bfA, accA, 0, 0, 0);
      accB = __builtin_amdgcn_mfma_f32_16x16x32_f16(afB, bfB, accB, 0, 0, 0);
    }
    if (kg < 2) {
#pragma unroll
      for (int r = 0; r < 4; ++r) gat[wave][kg * 4 + r][rowa] = accA[r] + accB[r];
    }
    if (lane < 32) {
      float gi = gat[wave][b][ju]      + gbi;
      float gf = gat[wave][b][4 + ju]  + gbf;
      float gg = gat[wave][b][8 + ju]  + gbg;
      float go = gat[wave][b][12 + ju] + gbo;
      c = sigm(gf) * c + sigm(gi) * ftanh(gg);
      float h = sigm(go) * ftanh(c);
      float hn = __shfl_down(h, 1);
      if ((ju & 1) == 0)
        STOREX(hseq + (size_t)(t + 1) * 2048 + (b * 256 + (uglob >> 1)), packf16(h, hn));
      hs[((size_t)b * S + t) * HH + uglob] = h;
    }
  }
}

// all three LSTMs in one dispatch (64 WGs)
__global__ __launch_bounds__(256, 1) void k_lstm3(
    const float* xp0, const f16* Whh0, u32* hseq0,
    const float* b1, const f16* Wih1, const f16* Whh1, u32* hseq1, float* h1s,
    const float* xpd, const f16* Whhd, u32* hseqD, float* hds) {
  int g = blockIdx.x;
  if (g < 16)      lstm_16(g, xp0, Whh0, hseq0, nullptr, TT);
  else if (g < 48) lstm_l1(g - 16, b1, Wih1, Whh1, hseq0, hseq1, h1s, TT);
  else             lstm_16(g - 48, xpd, Whhd, hseqD, hds, UU1);
}

// ------------------------------ fused joint --------------------------------
// Grid 1040 x 512thr. Z[128][520] built once in LDS; jW2 staged per
// (v-chunk, K-step) into double-buffered padded Bs (register-staged uint4,
// issued one step early). MFMA from LDS only. A=jW2(v), B=Z(m) -> f32x4 nt
// stores: v = kg*4-contiguous.
__global__ __launch_bounds__(512) void k_joint(
    const float* __restrict__ pre_enc,   // [B*T][512]   (bce folded in)
    const float* __restrict__ pre_dec,   // [B*65][512]  (bcd folded in)
    const f16* __restrict__ jW2,         // [1024][512] f16
    const float* __restrict__ jb2,
    float* __restrict__ out) {
  extern __shared__ char smem[];
  f16 (*Z)[520] = (f16(*)[520])smem;                        // 133,120 B
  f16 (*Bs)[64][72] = (f16(*)[64][72])(smem + 133120);      // 2 x 9,216 B
  int tid = threadIdx.x;
  int m0 = blockIdx.x * 128;
  {
    int r = tid >> 2, q = tid & 3;       // 4 threads per row, 128 cols each
    int m = m0 + r;
    int bb = m / (TT * UU1);
    int rem = m % (TT * UU1);
    int t = rem / UU1, u = rem % UU1;
    const float* pe = pre_enc + ((size_t)bb * TT + t) * JJ + q * 128;
    const float* pd = pre_dec + ((size_t)bb * UU1 + u) * JJ + q * 128;
    for (int i = 0; i < 128; i += 8) {
      float4 e0 = *(const float4*)(pe + i);
      float4 e1 = *(const float4*)(pe + i + 4);
      float4 d0 = *(const float4*)(pd + i);
      float4 d1 = *(const float4*)(pd + i + 4);
      float z0 = ftanh(e0.x + d0.x), z1 = ftanh(e0.y + d0.y);
      float z2 = ftanh(e0.z + d0.z), z3 = ftanh(e0.w + d0.w);
      float z4 = ftanh(e1.x + d1.x), z5 = ftanh(e1.y + d1.y);
      float z6 = ftanh(e1.z + d1.z), z7 = ftanh(e1.w + d1.w);
      uint4 p; p.x = packf16(z0, z1); p.y = packf16(z2, z3);
      p.z = packf16(z4, z5); p.w = packf16(z6, z7);
      *(uint4*)&Z[r][q * 128 + i] = p;
    }
  }
  const int wave = tid >> 6, lane = tid & 63;
  const int wm = wave >> 1, wn = wave & 1;   // 4 m-tiles(32) x 2 v-tiles(32)
  const int rowa = lane & 15, kg = lane >> 4;
  const int r8 = tid >> 3, c8 = tid & 7;     // stage: 64 rows x 8 octets

  // stage it=0 (vc=0, ks=0)
  {
    uint4 v = *(const uint4*)(jW2 + (size_t)r8 * JJ + c8 * 8);
    *(uint4*)&Bs[0][r8][c8 * 8] = v;
  }
  __syncthreads();   // Z + Bs[0] ready

  f32x4 acc[2][2] = {};
  for (int it = 0; it < 128; ++it) {
    const int buf = it & 1;
    uint4 nreg;
    if (it < 127) {
      int nvc = (it + 1) >> 3, nks = (it + 1) & 7;
      nreg = *(const uint4*)(jW2 + (size_t)(nvc * 64 + r8) * JJ + nks * 64 + c8 * 8);
    }
    const int ks = it & 7;
#pragma unroll
    for (int kf = 0; kf < 2; ++kf) {
      int zo = ks * 64 + kf * 32 + kg * 8;
      f16x8 af0 = *(const f16x8*)&Bs[buf][wn * 32 + rowa][kf * 32 + kg * 8];
      f16x8 af1 = *(const f16x8*)&Bs[buf][wn * 32 + 16 + rowa][kf * 32 + kg * 8];
      f16x8 bf0 = *(const f16x8*)&Z[wm * 32 + rowa][zo];
      f16x8 bf1 = *(const f16x8*)&Z[wm * 32 + 16 + rowa][zo];
      acc[0][0] = __builtin_amdgcn_mfma_f32_16x16x32_f16(af0, bf0, acc[0][0], 0, 0, 0);
      acc[0][1] = __builtin_amdgcn_mfma_f32_16x16x32_f16(af0, bf1, acc[0][1], 0, 0, 0);
      acc[1][0] = __builtin_amdgcn_mfma_f32_16x16x32_f16(af1, bf0, acc[1][0], 0, 0, 0);
      acc[1][1] = __builtin_amdgcn_mfma_f32_16x16x32_f16(af1, bf1, acc[1][1], 0, 0, 0);
    }
    if (ks == 7) {     // v-chunk complete: store
      int vc = it >> 3;
#pragma unroll
      for (int nt = 0; nt < 2; ++nt) {
        int v = vc * 64 + wn * 32 + nt * 16 + kg * 4;
        float4 bv = *(const float4*)(jb2 + v);
#pragma unroll
        for (int mt = 0; mt < 2; ++mt) {
          int m = m0 + wm * 32 + mt * 16 + rowa;
          f32x4 st;
          st[0] = acc[nt][mt][0] + bv.x;
          st[1] = acc[nt][mt][1] + bv.y;
          st[2] = acc[nt][mt][2] + bv.z;
          st[3] = acc[nt][mt][3] + bv.w;
          __builtin_nontemporal_store(st, (f32x4*)(out + (size_t)m * VV + v));
          acc[nt][mt] = (f32x4){0.f, 0.f, 0.f, 0.f};
        }
      }
    }
    __syncthreads();                 // all reads of Bs[buf^1] (prev it) done
    if (it < 127) *(uint4*)&Bs[buf ^ 1][r8][c8 * 8] = nreg;
    __syncthreads();                 // Bs[buf^1] ready
  }
}

// ------------------------------- host side ---------------------------------
extern "C" void kernel_launch(void* const* d_in, const int* in_sizes, int n_in,
                              void* d_out, int out_size, void* d_ws, size_t ws_size,
                              hipStream_t stream) {
  const float* xs    = (const float*)d_in[0];
  const int*   ys    = (const int*)d_in[1];
  const float* Wih0  = (const float*)d_in[2];
  const float* Whh0  = (const float*)d_in[3];
  const float* b0    = (const float*)d_in[4];
  const float* Wih1  = (const float*)d_in[5];
  const float* Whh1  = (const float*)d_in[6];
  const float* b1    = (const float*)d_in[7];
  const float* encPW = (const float*)d_in[8];
  const float* encPb = (const float*)d_in[9];
  const float* embed = (const float*)d_in[10];
  const float* dWih  = (const float*)d_in[11];
  const float* dWhh  = (const float*)d_in[12];
  const float* db    = (const float*)d_in[13];
  const float* dPW   = (const float*)d_in[14];
  const float* dPb   = (const float*)d_in[15];
  const float* jW1   = (const float*)d_in[16];
  const float* jb1   = (const float*)d_in[17];
  const float* jW2   = (const float*)d_in[18];
  const float* jb2   = (const float*)d_in[19];
  float* out = (float*)d_out;

  char* base = (char*)d_ws;
  size_t off = 0;
  auto alc = [&](size_t bytes) -> char* {
    char* p = base + off;
    off = (off + bytes + 255) & ~(size_t)255;
    return p;
  };
  f16* Wih0h = (f16*)alc((size_t)2048 * 80 * 2);
  f16* Whh0h = (f16*)alc((size_t)2048 * 512 * 2);
  f16* Wih1h = (f16*)alc((size_t)2048 * 512 * 2);
  f16* Whh1h = (f16*)alc((size_t)2048 * 512 * 2);
  f16* dWihh = (f16*)alc((size_t)2048 * 512 * 2);
  f16* dWhhh = (f16*)alc((size_t)2048 * 512 * 2);
  f16* ePWh  = (f16*)alc((size_t)512 * 512 * 2);
  f16* dPWh  = (f16*)alc((size_t)512 * 512 * 2);
  f16* jW2h  = (f16*)alc((size_t)1024 * 512 * 2);
  f16* Wceh  = (f16*)alc((size_t)512 * 512 * 2);   // jW1enc @ encPW
  f16* Wcdh  = (f16*)alc((size_t)512 * 512 * 2);   // jW1dec @ dPW
  float* bce  = (float*)alc((size_t)512 * 4);
  float* bcd  = (float*)alc((size_t)512 * 4);
  float* e    = (float*)alc((size_t)520 * 512 * 4);
  float* xp0  = (float*)alc((size_t)2048 * 2048 * 4);
  float* xpd  = (float*)alc((size_t)520 * 2048 * 4);
  float* h1s  = (float*)alc((size_t)2048 * 512 * 4);
  float* hds  = (float*)alc((size_t)520 * 512 * 4);
  float* penc = (float*)alc((size_t)2048 * 512 * 4);
  float* pdec = (float*)alc((size_t)520 * 512 * 4);
  u32* hseq0 = (u32*)alc((size_t)(TT + 1) * 2048 * 4);   // [257][2048]
  u32* hseq1 = (u32*)alc((size_t)(TT + 1) * 2048 * 4);   // [257][2048]
  u32* hseqD = (u32*)alc((size_t)(UU1 + 1) * 2048 * 4);  // [66][2048]
  if (off > ws_size) return;

  // 1) sentinel init (one launch): fill + zero slot 0 of each sequence
  {
    int n = (int)(((TT + 1) * 2 + (UU1 + 1)) * 2048);
    int z1 = (int)(hseq1 - hseq0), z2 = (int)(hseqD - hseq0);
    k_init<<<dim3((n + 255) / 256), dim3(256), 0, stream>>>(hseq0, n, z1, z2);
  }
  // 2) cast weights to f16 in ONE launch (jW1 stays f32 for k_gemmT)
  {
    CastArgs ca = {};
    auto seg = [&](int i, const float* s, f16* d, size_t n) {
      ca.seg[i].s = s; ca.seg[i].d = d; ca.seg[i].n4 = (int)(n / 4);
    };
    seg(0, Wih0, Wih0h, (size_t)2048 * 80);
    seg(1, Whh0, Whh0h, (size_t)2048 * 512);
    seg(2, Wih1, Wih1h, (size_t)2048 * 512);
    seg(3, Whh1, Whh1h, (size_t)2048 * 512);
    seg(4, dWih, dWihh, (size_t)2048 * 512);
    seg(5, dWhh, dWhhh, (size_t)2048 * 512);
    seg(6, encPW, ePWh, (size_t)512 * 512);
    seg(7, dPW, dPWh, (size_t)512 * 512);
    seg(8, jW2, jW2h, (size_t)1024 * 512);
    int total4 = 0;
    for (int i = 0; i < 9; ++i) total4 += ca.seg[i].n4;
    k_cast_all<<<dim3((total4 + 255) / 256), dim3(256), 0, stream>>>(ca, total4);
  }
  // 3) weight combine: Wce = jW1[:, :512] @ encPW ; Wcd = jW1[:, 512:] @ dPW
  k_gemmT<<<dim3(4, 4), dim3(256), 0, stream>>>(jW1, 1024, ePWh, Wceh);
  k_gemmT<<<dim3(4, 4), dim3(256), 0, stream>>>(jW1 + 512, 1024, dPWh, Wcdh);
  k_biasdot<<<dim3(2), dim3(256), 0, stream>>>(jW1, encPb, dPb, jb1, bce, bcd);

  // 4) embedding (decoder input)
  k_embed<<<dim3(520), dim3(128), 0, stream>>>(ys, embed, e);

  auto gemm = [&](const float* A, const f16* B, const float* bias, float* C,
                  int M, int N, int K, int lda, int ldb) {
    k_gemm<<<dim3(N / 128, (M + 127) / 128), dim3(256), 0, stream>>>(
        A, B, bias, C, M, N, K, lda, ldb);
  };

  // 5) input projections for enc L0 and decoder
  gemm(xs, Wih0h, b0, xp0, 2048, 2048, 80, 80, 80);
  gemm(e, dWihh, db, xpd, 520, 2048, 512, 512, 512);

  // 6) all three LSTMs, sentinel-pipelined, one dispatch (64 WGs)
  k_lstm3<<<dim3(64), dim3(256), 151168, stream>>>(
      xp0, Whh0h, hseq0,
      b1, Wih1h, Whh1h, hseq1, h1s,
      xpd, dWhhh, hseqD, hds);

  // 7) joint pre-activations directly from LSTM outputs (collapsed weights)
  gemm(h1s, Wceh, bce, penc, 2048, 512, 512, 512, 512);
  gemm(hds, Wcdh, bcd, pdec, 520, 512, 512, 512, 512);

  // 8) fused joint: z = tanh(penc+pdec) ; out = z @ jW2^T + jb2
  k_joint<<<dim3(1040), dim3(512), 151552, stream>>>(penc, pdec, jW2h, jb2, out);
}

// Round 12
// 1426.357 us; speedup vs baseline: 1.1624x; 1.0413x over previous
//
#include <hip/hip_runtime.h>

// ---------------------------------------------------------------------------
// Transducer forward (RNN-T). R11:
//  - k_joint: 64-row Z tile + single-buffer jW2 LDS stage = 75,776 B LDS
//    -> 2 blocks/CU (4 waves/SIMD) to hide barrier/L2 stalls. Grid 2080.
//  - LSTM/GEMMs unchanged from R10.
// Sync: per-step write-once sentinel buffers (0xFFFFFFFF = f16 NaN pair),
// guard-then-verify polling, RELAXED agent-scope atomics.
// ---------------------------------------------------------------------------

typedef _Float16 f16;
typedef _Float16 f16x8 __attribute__((ext_vector_type(8)));
typedef float f32x4 __attribute__((ext_vector_type(4)));
using u32 = unsigned int;

#define BB   8
#define TT   256
#define UU1  65      // U+1
#define HH   512
#define G4   2048    // 4*H
#define PP   512
#define JJ   512
#define VV   1024
#define SENT 0xFFFFFFFFu

#define LOADX(p)     __hip_atomic_load((p), __ATOMIC_RELAXED, __HIP_MEMORY_SCOPE_AGENT)
#define STOREX(p, v) __hip_atomic_store((p), (v), __ATOMIC_RELAXED, __HIP_MEMORY_SCOPE_AGENT)

static __device__ __forceinline__ u32 packf16(float a, float b) {
  f16 ha = (f16)a, hb = (f16)b;
  unsigned short ua = __builtin_bit_cast(unsigned short, ha);
  unsigned short ub = __builtin_bit_cast(unsigned short, hb);
  return (u32)ua | ((u32)ub << 16);
}
static __device__ __forceinline__ float sigm(float x) {
  x = fminf(30.f, fmaxf(-30.f, x));
  return __builtin_amdgcn_rcpf(1.f + __expf(-x));
}
static __device__ __forceinline__ float ftanh(float x) {
  x = fminf(15.f, fmaxf(-15.f, x));
  float t = __expf(2.f * x);
  return (t - 1.f) * __builtin_amdgcn_rcpf(t + 1.f);
}

// ---------------------------- utility kernels ------------------------------
__global__ void k_init(u32* __restrict__ p, int n, int z1, int z2) {
  int i = blockIdx.x * 256 + threadIdx.x;
  if (i >= n) return;
  bool z = (i < 2048) | ((u32)(i - z1) < 2048u) | ((u32)(i - z2) < 2048u);
  p[i] = z ? 0u : SENT;
}

struct CastSeg { const float* s; f16* d; int n4; };
struct CastArgs { CastSeg seg[10]; };
__global__ void k_cast_all(CastArgs a, int total4) {
  int i = blockIdx.x * 256 + threadIdx.x;
  if (i >= total4) return;
  int k = 0, off = i;
  while (off >= a.seg[k].n4) { off -= a.seg[k].n4; ++k; }
  const float4 v = *(const float4*)(a.seg[k].s + (size_t)off * 4);
  uint2 p; p.x = packf16(v.x, v.y); p.y = packf16(v.z, v.w);
  *(uint2*)(a.seg[k].d + (size_t)off * 4) = p;
}

// e[row][0:512] = embed[ys_p[row]] ; row = b*65+u ; ys_p[b][0]=BOS=0
__global__ void k_embed(const int* __restrict__ ys, const float* __restrict__ emb,
                        float* __restrict__ e) {
  int row = blockIdx.x;                 // 0..519
  int b = row / UU1, u = row % UU1;
  int idx = (u == 0) ? 0 : ys[b * (UU1 - 1) + (u - 1)];
  const float4* s = (const float4*)(emb + (size_t)idx * HH);
  float4* d = (float4*)(e + (size_t)row * HH);
  d[threadIdx.x] = s[threadIdx.x];      // 128 threads x 16B = 2KB
}

// bce[j] = dot(jW1[j, :512], encPb); bcd[j] = dot(jW1[j, 512:], dPb) + jb1[j]
__global__ void k_biasdot(const float* __restrict__ jW1, const float* __restrict__ encPb,
                          const float* __restrict__ dPb, const float* __restrict__ jb1,
                          float* __restrict__ bce, float* __restrict__ bcd) {
  int j = blockIdx.x * 256 + threadIdx.x;
  if (j >= 512) return;
  const float* rowE = jW1 + (size_t)j * 1024;
  const float* rowD = rowE + 512;
  float s1 = 0.f, s2 = 0.f;
  for (int p = 0; p < 512; p += 4) {
    float4 a = *(const float4*)(rowE + p), b = *(const float4*)(encPb + p);
    s1 += a.x * b.x + a.y * b.y + a.z * b.z + a.w * b.w;
    float4 c = *(const float4*)(rowD + p), d = *(const float4*)(dPb + p);
    s2 += c.x * d.x + c.y * d.y + c.z * d.z + c.w * d.w;
  }
  bce[j] = s1; bcd[j] = s2 + jb1[j];
}

// ------------------------------ generic GEMM -------------------------------
// C[M,N] = A[M,lda](f32) * B[N,ldb](f16)^T (+ bias[n]); MFMA f16 16x16x32.
__global__ __launch_bounds__(256) void k_gemm(
    const float* __restrict__ A, const f16* __restrict__ B,
    const float* __restrict__ bias, float* __restrict__ C,
    int M, int N, int K, int lda, int ldb) {
  __shared__ f16 As[128][72];
  __shared__ f16 Bs[128][72];
  int tid = threadIdx.x;
  int mb = blockIdx.y * 128, nb = blockIdx.x * 128;
  int wave = tid >> 6, lane = tid & 63;
  int wm = wave >> 1, wn = wave & 1;
  int rowa = lane & 15, kg = lane >> 4;
  f32x4 acc[4][4] = {};
  for (int k0 = 0; k0 < K; k0 += 64) {
    for (int idx = tid; idx < 2048; idx += 256) {
      int r = idx >> 4, cq = idx & 15;
      int gm = mb + r, gk = k0 + cq * 4;
      float4 v = make_float4(0.f, 0.f, 0.f, 0.f);
      if (gm < M && gk + 3 < K) v = *(const float4*)(A + (size_t)gm * lda + gk);
      uint2 p; p.x = packf16(v.x, v.y); p.y = packf16(v.z, v.w);
      *(uint2*)&As[r][cq * 4] = p;
    }
    for (int idx = tid; idx < 1024; idx += 256) {
      int r = idx >> 3, c8 = idx & 7;
      int gn = nb + r, gk = k0 + c8 * 8;
      uint4 v = make_uint4(0u, 0u, 0u, 0u);
      if (gn < N && gk + 7 < K) v = *(const uint4*)(B + (size_t)gn * ldb + gk);
      *(uint4*)&Bs[r][c8 * 8] = v;
    }
    __syncthreads();
#pragma unroll
    for (int kf = 0; kf < 2; ++kf) {
      f16x8 af[4], bf[4];
#pragma unroll
      for (int mt = 0; mt < 4; ++mt)
        af[mt] = *(const f16x8*)&As[wm * 64 + mt * 16 + rowa][kf * 32 + kg * 8];
#pragma unroll
      for (int nt = 0; nt < 4; ++nt)
        bf[nt] = *(const f16x8*)&Bs[wn * 64 + nt * 16 + rowa][kf * 32 + kg * 8];
#pragma unroll
      for (int mt = 0; mt < 4; ++mt)
#pragma unroll
        for (int nt = 0; nt < 4; ++nt)
          acc[mt][nt] = __builtin_amdgcn_mfma_f32_16x16x32_f16(af[mt], bf[nt], acc[mt][nt], 0, 0, 0);
    }
    __syncthreads();
  }
#pragma unroll
  for (int nt = 0; nt < 4; ++nt) {
    int gn = nb + wn * 64 + nt * 16 + rowa;
    float bv = bias ? bias[gn] : 0.f;
#pragma unroll
    for (int mt = 0; mt < 4; ++mt)
#pragma unroll
      for (int r = 0; r < 4; ++r) {
        int gm = mb + wm * 64 + mt * 16 + kg * 4 + r;
        if (gm < M) C[(size_t)gm * N + gn] = acc[mt][nt][r] + bv;
      }
  }
}

// ---------------- transposed-B GEMM (weight combine, 512^3) ----------------
// C16[j][h] = sum_p A[j][p](f32) * B2[p][h](f16); M=N=K=512 exact.
__global__ __launch_bounds__(256) void k_gemmT(
    const float* __restrict__ A, int lda, const f16* __restrict__ B2,
    f16* __restrict__ C16) {
  __shared__ f16 As[128][72];
  __shared__ f16 Bs[128][72];
  int tid = threadIdx.x;
  int mb = blockIdx.y * 128, nb = blockIdx.x * 128;
  int wave = tid >> 6, lane = tid & 63;
  int wm = wave >> 1, wn = wave & 1;
  int rowa = lane & 15, kg = lane >> 4;
  f32x4 acc[4][4] = {};
  for (int k0 = 0; k0 < 512; k0 += 64) {
    for (int idx = tid; idx < 2048; idx += 256) {
      int r = idx >> 4, cq = idx & 15;
      float4 v = *(const float4*)(A + (size_t)(mb + r) * lda + k0 + cq * 4);
      uint2 p; p.x = packf16(v.x, v.y); p.y = packf16(v.z, v.w);
      *(uint2*)&As[r][cq * 4] = p;
    }
    for (int idx = tid; idx < 1024; idx += 256) {
      int r = idx >> 4, c8 = idx & 15;          // r = k 0..63, c8 = n-octet
      uint4 v = *(const uint4*)(B2 + (size_t)(k0 + r) * 512 + nb + c8 * 8);
      f16 tmp[8]; *(uint4*)tmp = v;
#pragma unroll
      for (int e = 0; e < 8; ++e) Bs[c8 * 8 + e][r] = tmp[e];
    }
    __syncthreads();
#pragma unroll
    for (int kf = 0; kf < 2; ++kf) {
      f16x8 af[4], bf[4];
#pragma unroll
      for (int mt = 0; mt < 4; ++mt)
        af[mt] = *(const f16x8*)&As[wm * 64 + mt * 16 + rowa][kf * 32 + kg * 8];
#pragma unroll
      for (int nt = 0; nt < 4; ++nt)
        bf[nt] = *(const f16x8*)&Bs[wn * 64 + nt * 16 + rowa][kf * 32 + kg * 8];
#pragma unroll
      for (int mt = 0; mt < 4; ++mt)
#pragma unroll
        for (int nt = 0; nt < 4; ++nt)
          acc[mt][nt] = __builtin_amdgcn_mfma_f32_16x16x32_f16(af[mt], bf[nt], acc[mt][nt], 0, 0, 0);
    }
    __syncthreads();
  }
#pragma unroll
  for (int nt = 0; nt < 4; ++nt) {
    int gn = nb + wn * 64 + nt * 16 + rowa;
#pragma unroll
    for (int mt = 0; mt < 4; ++mt)
#pragma unroll
      for (int r = 0; r < 4; ++r) {
        int gm = mb + wm * 64 + mt * 16 + kg * 4 + r;
        C16[(size_t)gm * 512 + gn] = (f16)acc[mt][nt][r];
      }
  }
}

// --------------------- persistent LSTM, sentinel-synced --------------------
template <int NW>
static __device__ __forceinline__ void poll_batch(const u32* const* p, u32* vv) {
#pragma unroll
  for (int k = 0; k < NW; ++k) vv[k] = LOADX(p[k]);   // all in flight
  int gd = 0;
  while (++gd < (1 << 18)) {
    bool any = false;
#pragma unroll
    for (int k = 0; k < NW; ++k) any = any | (vv[k] == SENT);
    if (!any) break;
    __builtin_amdgcn_s_sleep(4);
#pragma unroll
    for (int k = 0; k < NW; ++k)
      if (vv[k] == SENT) vv[k] = LOADX(p[k]);
  }
}
static __device__ __forceinline__ void guard_spin(const u32* gp) {
  u32 v = LOADX(gp);
  int gd = 0;
  while (v == SENT && ++gd < (1 << 18)) {
    __builtin_amdgcn_s_sleep(2);
    v = LOADX(gp);
  }
}

// 32-unit WG (L0 / decoder). Wave w owns units [w*8, w*8+8), ALL 4 gates.
static __device__ __forceinline__ void lstm_16(
    int wg, const float* __restrict__ xp, const f16* __restrict__ Whh,
    u32* __restrict__ hseq,   // [S+1][2048]; slot 0 zeroed, rest sentinel
    float* __restrict__ hs, int S) {
  extern __shared__ char smem[];
  f16 (*W)[520] = (f16(*)[520])smem;                       // 133,120 B
  f16 (*H)[520] = (f16(*)[520])(smem + 133120);            //   8,320 B
  float (*gat)[8][36] = (float(*)[8][36])(smem + 133120 + 8320); // 4,608 B
  const int tid = threadIdx.x;
  const int u0 = wg * 32;
  const int wave = tid >> 6, lane = tid & 63;
  const int rowa = lane & 15, kg = lane >> 4;
  const int b = lane >> 3, ju = lane & 7;          // scalar-phase mapping
  const int uglob = u0 + wave * 8 + ju;

  for (int idx = tid; idx < 128 * 64; idx += 256) {
    int r = idx >> 6, ck = idx & 63;
    int w = r >> 5, g = (r >> 3) & 3, u = r & 7;
    uint4 v = *(const uint4*)(Whh + ((size_t)(g * 512 + u0 + w * 8 + u)) * 512 + ck * 8);
    *(uint4*)&W[r][ck * 8] = v;
  }
  __syncthreads();

  float c = 0.f;
  for (int t = 0; t < S; ++t) {
    const u32* hb = hseq + (size_t)t * 2048;
    if (tid < 16) guard_spin(hb + tid * 16);
    __syncthreads();

    size_t xpo = ((size_t)b * S + t) * (size_t)G4 + uglob;
    float xi = xp[xpo], xf = xp[xpo + 512], xg = xp[xpo + 1024], xo = xp[xpo + 1536];

    const u32* ptr[8];
    u32 vv[8];
#pragma unroll
    for (int k = 0; k < 8; ++k) ptr[k] = hb + ((tid + k * 256) >> 8) * 256 + ((tid + k * 256) & 255);
    poll_batch<8>(ptr, vv);
#pragma unroll
    for (int k = 0; k < 8; ++k) {
      int idx = tid + k * 256;
      ((u32*)H)[(idx >> 8) * 260 + (idx & 255)] = vv[k];
    }
    __syncthreads();  // B2: H ready

    f32x4 acc0 = {0.f, 0.f, 0.f, 0.f}, acc1 = {0.f, 0.f, 0.f, 0.f};
#pragma unroll
    for (int kf = 0; kf < 16; ++kf) {
      f16x8 af = {};
      if (rowa < 8) af = *(const f16x8*)&H[rowa][kf * 32 + kg * 8];
      f16x8 b0 = *(const f16x8*)&W[wave * 32 + rowa][kf * 32 + kg * 8];
      f16x8 b1 = *(const f16x8*)&W[wave * 32 + 16 + rowa][kf * 32 + kg * 8];
      acc0 = __builtin_amdgcn_mfma_f32_16x16x32_f16(af, b0, acc0, 0, 0, 0);
      acc1 = __builtin_amdgcn_mfma_f32_16x16x32_f16(af, b1, acc1, 0, 0, 0);
    }
    if (kg < 2) {
#pragma unroll
      for (int r = 0; r < 4; ++r) {
        gat[wave][kg * 4 + r][rowa] = acc0[r];
        gat[wave][kg * 4 + r][16 + rowa] = acc1[r];
      }
    }
    // wave-local read (lgkmcnt wait auto-inserted; no barrier)
    float gi = gat[wave][b][ju] + xi;
    float gf = gat[wave][b][8 + ju] + xf;
    float gg = gat[wave][b][16 + ju] + xg;
    float go = gat[wave][b][24 + ju] + xo;
    c = sigm(gf) * c + sigm(gi) * ftanh(gg);
    float h = sigm(go) * ftanh(c);

    float hn = __shfl_down(h, 1);
    if ((ju & 1) == 0)
      STOREX(hseq + (size_t)(t + 1) * 2048 + ((b * 512 + uglob) >> 1), packf16(h, hn));
    if (hs) hs[((size_t)b * S + t) * HH + uglob] = h;
  }
}

// 16-unit WG (encoder L1): combined poll (16 words), split accumulators.
static __device__ __forceinline__ void lstm_l1(
    int wg, const float* __restrict__ gb, const f16* __restrict__ Wih,
    const f16* __restrict__ Whh, const u32* __restrict__ hin,
    u32* __restrict__ hseq, float* __restrict__ hs, int S) {
  extern __shared__ char smem[];
  f16 (*W)[1032] = (f16(*)[1032])smem;                      // 132,096 B
  f16 (*H)[1032] = (f16(*)[1032])(smem + 132096);           //  16,512 B
  float (*gat)[8][20] = (float(*)[8][20])(smem + 132096 + 16512); // 2,560 B
  const int tid = threadIdx.x;
  const int u0 = wg * 16;
  const int wave = tid >> 6, lane = tid & 63;
  const int rowa = lane & 15, kg = lane >> 4;
  const int b = lane >> 2, ju = lane & 3;   // valid for lane < 32
  const int uglob = u0 + wave * 4 + ju;

  for (int idx = tid; idx < 64 * 64; idx += 256) {
    int r = idx >> 6, ck = idx & 63;
    int w = r >> 4, g = (r >> 2) & 3, u = r & 3;
    size_t grow = (size_t)(g * 512 + u0 + w * 4 + u) * 512;
    *(uint4*)&W[r][ck * 8]       = *(const uint4*)(Whh + grow + ck * 8);
    *(uint4*)&W[r][512 + ck * 8] = *(const uint4*)(Wih + grow + ck * 8);
  }
  float gbi = 0.f, gbf = 0.f, gbg = 0.f, gbo = 0.f;
  if (lane < 32) {
    gbi = gb[uglob]; gbf = gb[512 + uglob];
    gbg = gb[1024 + uglob]; gbo = gb[1536 + uglob];
  }
  __syncthreads();

  float c = 0.f;
  for (int t = 0; t < S; ++t) {
    const u32* hbS = hseq + (size_t)t * 2048;
    const u32* hbU = hin + (size_t)(t + 1) * 2048;
    if (tid < 32)       guard_spin(hbS + tid * 8);
    else if (tid < 48)  guard_spin(hbU + (tid - 32) * 16);
    __syncthreads();
    const u32* ptr[16];
    u32 vv[16];
#pragma unroll
    for (int k = 0; k < 8; ++k) {
      int idx = tid + k * 256;
      int r = idx >> 8, cu = idx & 255;
      ptr[k] = hbS + r * 256 + cu;
      ptr[k + 8] = hbU + r * 256 + cu;
    }
    poll_batch<16>(ptr, vv);
#pragma unroll
    for (int k = 0; k < 8; ++k) {
      int idx = tid + k * 256;
      int r = idx >> 8, cu = idx & 255;
      ((u32*)H)[r * 516 + cu] = vv[k];
      ((u32*)H)[r * 516 + 256 + cu] = vv[k + 8];
    }
    __syncthreads();  // B2

    f32x4 accA = {0.f, 0.f, 0.f, 0.f}, accB = {0.f, 0.f, 0.f, 0.f};
#pragma unroll
    for (int kf = 0; kf < 16; ++kf) {
      f16x8 afA = {}, afB = {};
      if (rowa < 8) {
        afA = *(const f16x8*)&H[rowa][kf * 32 + kg * 8];
        afB = *(const f16x8*)&H[rowa][(kf + 16) * 32 + kg * 8];
      }
      f16x8 bfA = *(const f16x8*)&W[wave * 16 + rowa][kf * 32 + kg * 8];
      f16x8 bfB = *(const f16x8*)&W[wave * 16 + rowa][(kf + 16) * 32 + kg * 8];
      accA = __builtin_amdgcn_mfma_f32_16x16x32_f16(afA, bfA, accA, 0, 0, 0);
      accB = __builtin_amdgcn_mfma_f32_16x16x32_f16(afB, bfB, accB, 0, 0, 0);
    }
    if (kg < 2) {
#pragma unroll
      for (int r = 0; r < 4; ++r) gat[wave][kg * 4 + r][rowa] = accA[r] + accB[r];
    }
    if (lane < 32) {
      float gi = gat[wave][b][ju]      + gbi;
      float gf = gat[wave][b][4 + ju]  + gbf;
      float gg = gat[wave][b][8 + ju]  + gbg;
      float go = gat[wave][b][12 + ju] + gbo;
      c = sigm(gf) * c + sigm(gi) * ftanh(gg);
      float h = sigm(go) * ftanh(c);
      float hn = __shfl_down(h, 1);
      if ((ju & 1) == 0)
        STOREX(hseq + (size_t)(t + 1) * 2048 + (b * 256 + (uglob >> 1)), packf16(h, hn));
      hs[((size_t)b * S + t) * HH + uglob] = h;
    }
  }
}

// all three LSTMs in one dispatch (64 WGs)
__global__ __launch_bounds__(256, 1) void k_lstm3(
    const float* xp0, const f16* Whh0, u32* hseq0,
    const float* b1, const f16* Wih1, const f16* Whh1, u32* hseq1, float* h1s,
    const float* xpd, const f16* Whhd, u32* hseqD, float* hds) {
  int g = blockIdx.x;
  if (g < 16)      lstm_16(g, xp0, Whh0, hseq0, nullptr, TT);
  else if (g < 48) lstm_l1(g - 16, b1, Wih1, Whh1, hseq0, hseq1, h1s, TT);
  else             lstm_16(g - 48, xpd, Whhd, hseqD, hds, UU1);
}

// ------------------------------ fused joint --------------------------------
// Grid 2080 x 512thr, LDS 75,776 B -> 2 blocks/CU (4 waves/SIMD).
// Z[64][520] built once; jW2 staged per (v-chunk, K-step) into SINGLE-buffer
// Bs[64][72] (register preload one it early). A=jW2(v), B=Z(m) -> f32x4 nt
// stores (v contiguous per lane).
__global__ __launch_bounds__(512, 4) void k_joint(
    const float* __restrict__ pre_enc,   // [B*T][512]   (bce folded in)
    const float* __restrict__ pre_dec,   // [B*65][512]  (bcd folded in)
    const f16* __restrict__ jW2,         // [1024][512] f16
    const float* __restrict__ jb2,
    float* __restrict__ out) {
  extern __shared__ char smem[];
  f16 (*Z)[520] = (f16(*)[520])smem;                     // 66,560 B
  f16 (*Bs)[72] = (f16(*)[72])(smem + 66560);            //  9,216 B
  int tid = threadIdx.x;
  int m0 = blockIdx.x * 64;
  {
    int r = tid >> 3, q = tid & 7;       // 8 threads per row, 64 cols each
    int m = m0 + r;
    int bb = m / (TT * UU1);
    int rem = m % (TT * UU1);
    int t = rem / UU1, u = rem % UU1;
    const float* pe = pre_enc + ((size_t)bb * TT + t) * JJ + q * 64;
    const float* pd = pre_dec + ((size_t)bb * UU1 + u) * JJ + q * 64;
    for (int i = 0; i < 64; i += 8) {
      float4 e0 = *(const float4*)(pe + i);
      float4 e1 = *(const float4*)(pe + i + 4);
      float4 d0 = *(const float4*)(pd + i);
      float4 d1 = *(const float4*)(pd + i + 4);
      float z0 = ftanh(e0.x + d0.x), z1 = ftanh(e0.y + d0.y);
      float z2 = ftanh(e0.z + d0.z), z3 = ftanh(e0.w + d0.w);
      float z4 = ftanh(e1.x + d1.x), z5 = ftanh(e1.y + d1.y);
      float z6 = ftanh(e1.z + d1.z), z7 = ftanh(e1.w + d1.w);
      uint4 p; p.x = packf16(z0, z1); p.y = packf16(z2, z3);
      p.z = packf16(z4, z5); p.w = packf16(z6, z7);
      *(uint4*)&Z[r][q * 64 + i] = p;
    }
  }
  const int wave = tid >> 6, lane = tid & 63;
  const int wm = wave >> 2, wn = wave & 3;   // 2 m-tiles(32) x 4 v-tiles(16)
  const int rowa = lane & 15, kg = lane >> 4;
  const int r8 = tid >> 3, c8 = tid & 7;     // stage: 64 rows x 8 octets

  // preload it=0 slice (vc=0, ks=0)
  uint4 nreg = *(const uint4*)(jW2 + (size_t)r8 * JJ + c8 * 8);

  f32x4 acc[2] = {};
  for (int it = 0; it < 128; ++it) {
    const int vc = it >> 3, ks = it & 7;
    __syncthreads();                 // it=0: Z ready; else: Bs reads drained
    *(uint4*)&Bs[r8][c8 * 8] = nreg;
    if (it < 127) {                  // issue next slice load early
      int nvc = (it + 1) >> 3, nks = (it + 1) & 7;
      nreg = *(const uint4*)(jW2 + (size_t)(nvc * 64 + r8) * JJ + nks * 64 + c8 * 8);
    }
    __syncthreads();                 // Bs published
#pragma unroll
    for (int kf = 0; kf < 2; ++kf) {
      int zo = ks * 64 + kf * 32 + kg * 8;
      f16x8 af  = *(const f16x8*)&Bs[wn * 16 + rowa][kf * 32 + kg * 8];
      f16x8 bf0 = *(const f16x8*)&Z[wm * 32 + rowa][zo];
      f16x8 bf1 = *(const f16x8*)&Z[wm * 32 + 16 + rowa][zo];
      acc[0] = __builtin_amdgcn_mfma_f32_16x16x32_f16(af, bf0, acc[0], 0, 0, 0);
      acc[1] = __builtin_amdgcn_mfma_f32_16x16x32_f16(af, bf1, acc[1], 0, 0, 0);
    }
    if (ks == 7) {     // v-chunk complete: store
      int v = vc * 64 + wn * 16 + kg * 4;
      float4 bv = *(const float4*)(jb2 + v);
#pragma unroll
      for (int mt = 0; mt < 2; ++mt) {
        int m = m0 + wm * 32 + mt * 16 + rowa;
        f32x4 st;
        st[0] = acc[mt][0] + bv.x;
        st[1] = acc[mt][1] + bv.y;
        st[2] = acc[mt][2] + bv.z;
        st[3] = acc[mt][3] + bv.w;
        __builtin_nontemporal_store(st, (f32x4*)(out + (size_t)m * VV + v));
        acc[mt] = (f32x4){0.f, 0.f, 0.f, 0.f};
      }
    }
  }
}

// ------------------------------- host side ---------------------------------
extern "C" void kernel_launch(void* const* d_in, const int* in_sizes, int n_in,
                              void* d_out, int out_size, void* d_ws, size_t ws_size,
                              hipStream_t stream) {
  const float* xs    = (const float*)d_in[0];
  const int*   ys    = (const int*)d_in[1];
  const float* Wih0  = (const float*)d_in[2];
  const float* Whh0  = (const float*)d_in[3];
  const float* b0    = (const float*)d_in[4];
  const float* Wih1  = (const float*)d_in[5];
  const float* Whh1  = (const float*)d_in[6];
  const float* b1    = (const float*)d_in[7];
  const float* encPW = (const float*)d_in[8];
  const float* encPb = (const float*)d_in[9];
  const float* embed = (const float*)d_in[10];
  const float* dWih  = (const float*)d_in[11];
  const float* dWhh  = (const float*)d_in[12];
  const float* db    = (const float*)d_in[13];
  const float* dPW   = (const float*)d_in[14];
  const float* dPb   = (const float*)d_in[15];
  const float* jW1   = (const float*)d_in[16];
  const float* jb1   = (const float*)d_in[17];
  const float* jW2   = (const float*)d_in[18];
  const float* jb2   = (const float*)d_in[19];
  float* out = (float*)d_out;

  char* base = (char*)d_ws;
  size_t off = 0;
  auto alc = [&](size_t bytes) -> char* {
    char* p = base + off;
    off = (off + bytes + 255) & ~(size_t)255;
    return p;
  };
  f16* Wih0h = (f16*)alc((size_t)2048 * 80 * 2);
  f16* Whh0h = (f16*)alc((size_t)2048 * 512 * 2);
  f16* Wih1h = (f16*)alc((size_t)2048 * 512 * 2);
  f16* Whh1h = (f16*)alc((size_t)2048 * 512 * 2);
  f16* dWihh = (f16*)alc((size_t)2048 * 512 * 2);
  f16* dWhhh = (f16*)alc((size_t)2048 * 512 * 2);
  f16* ePWh  = (f16*)alc((size_t)512 * 512 * 2);
  f16* dPWh  = (f16*)alc((size_t)512 * 512 * 2);
  f16* jW2h  = (f16*)alc((size_t)1024 * 512 * 2);
  f16* Wceh  = (f16*)alc((size_t)512 * 512 * 2);   // jW1enc @ encPW
  f16* Wcdh  = (f16*)alc((size_t)512 * 512 * 2);   // jW1dec @ dPW
  float* bce  = (float*)alc((size_t)512 * 4);
  float* bcd  = (float*)alc((size_t)512 * 4);
  float* e    = (float*)alc((size_t)520 * 512 * 4);
  float* xp0  = (float*)alc((size_t)2048 * 2048 * 4);
  float* xpd  = (float*)alc((size_t)520 * 2048 * 4);
  float* h1s  = (float*)alc((size_t)2048 * 512 * 4);
  float* hds  = (float*)alc((size_t)520 * 512 * 4);
  float* penc = (float*)alc((size_t)2048 * 512 * 4);
  float* pdec = (float*)alc((size_t)520 * 512 * 4);
  u32* hseq0 = (u32*)alc((size_t)(TT + 1) * 2048 * 4);   // [257][2048]
  u32* hseq1 = (u32*)alc((size_t)(TT + 1) * 2048 * 4);   // [257][2048]
  u32* hseqD = (u32*)alc((size_t)(UU1 + 1) * 2048 * 4);  // [66][2048]
  if (off > ws_size) return;

  // 1) sentinel init (one launch): fill + zero slot 0 of each sequence
  {
    int n = (int)(((TT + 1) * 2 + (UU1 + 1)) * 2048);
    int z1 = (int)(hseq1 - hseq0), z2 = (int)(hseqD - hseq0);
    k_init<<<dim3((n + 255) / 256), dim3(256), 0, stream>>>(hseq0, n, z1, z2);
  }
  // 2) cast weights to f16 in ONE launch (jW1 stays f32 for k_gemmT)
  {
    CastArgs ca = {};
    auto seg = [&](int i, const float* s, f16* d, size_t n) {
      ca.seg[i].s = s; ca.seg[i].d = d; ca.seg[i].n4 = (int)(n / 4);
    };
    seg(0, Wih0, Wih0h, (size_t)2048 * 80);
    seg(1, Whh0, Whh0h, (size_t)2048 * 512);
    seg(2, Wih1, Wih1h, (size_t)2048 * 512);
    seg(3, Whh1, Whh1h, (size_t)2048 * 512);
    seg(4, dWih, dWihh, (size_t)2048 * 512);
    seg(5, dWhh, dWhhh, (size_t)2048 * 512);
    seg(6, encPW, ePWh, (size_t)512 * 512);
    seg(7, dPW, dPWh, (size_t)512 * 512);
    seg(8, jW2, jW2h, (size_t)1024 * 512);
    int total4 = 0;
    for (int i = 0; i < 9; ++i) total4 += ca.seg[i].n4;
    k_cast_all<<<dim3((total4 + 255) / 256), dim3(256), 0, stream>>>(ca, total4);
  }
  // 3) weight combine: Wce = jW1[:, :512] @ encPW ; Wcd = jW1[:, 512:] @ dPW
  k_gemmT<<<dim3(4, 4), dim3(256), 0, stream>>>(jW1, 1024, ePWh, Wceh);
  k_gemmT<<<dim3(4, 4), dim3(256), 0, stream>>>(jW1 + 512, 1024, dPWh, Wcdh);
  k_biasdot<<<dim3(2), dim3(256), 0, stream>>>(jW1, encPb, dPb, jb1, bce, bcd);

  // 4) embedding (decoder input)
  k_embed<<<dim3(520), dim3(128), 0, stream>>>(ys, embed, e);

  auto gemm = [&](const float* A, const f16* B, const float* bias, float* C,
                  int M, int N, int K, int lda, int ldb) {
    k_gemm<<<dim3(N / 128, (M + 127) / 128), dim3(256), 0, stream>>>(
        A, B, bias, C, M, N, K, lda, ldb);
  };

  // 5) input projections for enc L0 and decoder
  gemm(xs, Wih0h, b0, xp0, 2048, 2048, 80, 80, 80);
  gemm(e, dWihh, db, xpd, 520, 2048, 512, 512, 512);

  // 6) all three LSTMs, sentinel-pipelined, one dispatch (64 WGs)
  k_lstm3<<<dim3(64), dim3(256), 151168, stream>>>(
      xp0, Whh0h, hseq0,
      b1, Wih1h, Whh1h, hseq1, h1s,
      xpd, dWhhh, hseqD, hds);

  // 7) joint pre-activations directly from LSTM outputs (collapsed weights)
  gemm(h1s, Wceh, bce, penc, 2048, 512, 512, 512, 512);
  gemm(hds, Wcdh, bcd, pdec, 520, 512, 512, 512, 512);

  // 8) fused joint: z = tanh(penc+pdec) ; out = z @ jW2^T + jb2
  k_joint<<<dim3(2080), dim3(512), 75776, stream>>>(penc, pdec, jW2h, jb2, out);
}